// Round 1
// baseline (12230.897 us; speedup 1.0000x reference)
//
#include <hip/hip_runtime.h>

constexpr int D   = 128;
constexpr int G   = 64;
constexpr int OUT = 64;
constexpr int L   = 4;
#define BN_EPS 1e-5f

// ---------------------------------------------------------------- scatter
__global__ void scatter_agg(const float* __restrict__ h, const int* __restrict__ src,
                            const int* __restrict__ dst, float* __restrict__ agg, int nE) {
    long long idx = (long long)blockIdx.x * blockDim.x + threadIdx.x;
    if (idx >= (long long)nE * 32) return;
    int e = (int)(idx >> 5);
    int q = (int)(idx & 31);
    int s = src[e], d = dst[e];
    float4 v = *reinterpret_cast<const float4*>(h + (long long)s * D + q * 4);
    float* p = agg + (long long)d * D + q * 4;
    atomicAdd(p + 0, v.x);
    atomicAdd(p + 1, v.y);
    atomicAdd(p + 2, v.z);
    atomicAdd(p + 3, v.w);
}

// ---------------------------------------------------------------- GEMM (N x 128) @ (128 x 128) + bias, fused input transform + BN-stat epilogue
// MODE 0: A(row,k) = (1+eps)*in0 + in1      (GIN combine)
// MODE 1: A(row,k) = relu(in0*scale[k] + shift[k])   (BN+ReLU on the fly)
template <int MODE>
__global__ __launch_bounds__(512) void gemm128(
    const float* __restrict__ in0, const float* __restrict__ in1,
    const float* __restrict__ scale, const float* __restrict__ shift,
    const float* __restrict__ epsP,
    const float* __restrict__ W, const float* __restrict__ bias,
    float* __restrict__ out, float* __restrict__ gsum, float* __restrict__ gsq,
    int nRows) {
    __shared__ float wL[D * D];          // 64 KB
    __shared__ float aL[64][D + 1];      // 33 KB (padded: conflict-free column reads)
    __shared__ float redS[D];
    __shared__ float redQ[D];

    const int tid = threadIdx.x;
    const long long row0 = (long long)blockIdx.x * 64;

    // stage W (full 128x128) into LDS
    for (int i = tid * 4; i < D * D; i += 512 * 4)
        *reinterpret_cast<float4*>(&wL[i]) = *reinterpret_cast<const float4*>(&W[i]);

    const float ep = (MODE == 0) ? (1.0f + epsP[0]) : 0.0f;

    // stage A tile (64 rows) with fused transform
    for (int i = tid; i < 64 * 32; i += 512) {
        int r = i >> 5, q = i & 31;
        long long row = row0 + r;
        float4 v = make_float4(0.f, 0.f, 0.f, 0.f);
        if (row < nRows) {
            v = *reinterpret_cast<const float4*>(in0 + row * D + q * 4);
            if (MODE == 0) {
                float4 a = *reinterpret_cast<const float4*>(in1 + row * D + q * 4);
                v.x = ep * v.x + a.x;
                v.y = ep * v.y + a.y;
                v.z = ep * v.z + a.z;
                v.w = ep * v.w + a.w;
            } else {
                int c = q * 4;
                v.x = fmaxf(v.x * scale[c + 0] + shift[c + 0], 0.f);
                v.y = fmaxf(v.y * scale[c + 1] + shift[c + 1], 0.f);
                v.z = fmaxf(v.z * scale[c + 2] + shift[c + 2], 0.f);
                v.w = fmaxf(v.w * scale[c + 3] + shift[c + 3], 0.f);
            }
        }
        aL[r][q * 4 + 0] = v.x;
        aL[r][q * 4 + 1] = v.y;
        aL[r][q * 4 + 2] = v.z;
        aL[r][q * 4 + 3] = v.w;
    }
    if (tid < D) { redS[tid] = 0.f; redQ[tid] = 0.f; }
    __syncthreads();

    const int ct = tid & 31, rt = tid >> 5;    // 32 col-threads x 16 row-threads
    const int c0 = ct * 4, r0 = rt * 4;        // each thread: 4 rows x 4 cols
    float acc[4][4] = {};
#pragma unroll 4
    for (int k = 0; k < D; ++k) {
        float4 wv = *reinterpret_cast<const float4*>(&wL[k * D + c0]);
        float a0 = aL[r0 + 0][k];
        float a1 = aL[r0 + 1][k];
        float a2 = aL[r0 + 2][k];
        float a3 = aL[r0 + 3][k];
        acc[0][0] += a0 * wv.x; acc[0][1] += a0 * wv.y; acc[0][2] += a0 * wv.z; acc[0][3] += a0 * wv.w;
        acc[1][0] += a1 * wv.x; acc[1][1] += a1 * wv.y; acc[1][2] += a1 * wv.z; acc[1][3] += a1 * wv.w;
        acc[2][0] += a2 * wv.x; acc[2][1] += a2 * wv.y; acc[2][2] += a2 * wv.z; acc[2][3] += a2 * wv.w;
        acc[3][0] += a3 * wv.x; acc[3][1] += a3 * wv.y; acc[3][2] += a3 * wv.z; acc[3][3] += a3 * wv.w;
    }

    const float4 bv = *reinterpret_cast<const float4*>(bias + c0);
    float lsum[4] = {}, lsq[4] = {};
#pragma unroll
    for (int i = 0; i < 4; ++i) {
        long long row = row0 + r0 + i;
        if (row < nRows) {
            float4 o;
            o.x = acc[i][0] + bv.x;
            o.y = acc[i][1] + bv.y;
            o.z = acc[i][2] + bv.z;
            o.w = acc[i][3] + bv.w;
            *reinterpret_cast<float4*>(out + row * D + c0) = o;
            lsum[0] += o.x; lsq[0] += o.x * o.x;
            lsum[1] += o.y; lsq[1] += o.y * o.y;
            lsum[2] += o.z; lsq[2] += o.z * o.z;
            lsum[3] += o.w; lsq[3] += o.w * o.w;
        }
    }
    atomicAdd(&redS[c0 + 0], lsum[0]);
    atomicAdd(&redS[c0 + 1], lsum[1]);
    atomicAdd(&redS[c0 + 2], lsum[2]);
    atomicAdd(&redS[c0 + 3], lsum[3]);
    atomicAdd(&redQ[c0 + 0], lsq[0]);
    atomicAdd(&redQ[c0 + 1], lsq[1]);
    atomicAdd(&redQ[c0 + 2], lsq[2]);
    atomicAdd(&redQ[c0 + 3], lsq[3]);
    __syncthreads();
    if (tid < D) {
        atomicAdd(&gsum[tid], redS[tid]);
        atomicAdd(&gsq[tid], redQ[tid]);
    }
}

// ---------------------------------------------------------------- BN finalize: scale/shift from sums
__global__ void bn_finalize(const float* __restrict__ gsum, const float* __restrict__ gsq,
                            const float* __restrict__ g, const float* __restrict__ b,
                            float invN, float* __restrict__ scale, float* __restrict__ shift) {
    int c = threadIdx.x;
    float m = gsum[c] * invN;
    float v = gsq[c] * invN - m * m;
    float inv = rsqrtf(v + BN_EPS);
    float sc = g[c] * inv;
    scale[c] = sc;
    shift[c] = b[c] - m * sc;
}

// ---------------------------------------------------------------- stats of relu(bn2(z)) without materializing
__global__ void relu_bn_stats(const float* __restrict__ z,
                              const float* __restrict__ scale, const float* __restrict__ shift,
                              float* __restrict__ gsum, float* __restrict__ gsq, long long n4) {
    __shared__ float redS[D], redQ[D];
    const int tid = threadIdx.x;
    if (tid < D) { redS[tid] = 0.f; redQ[tid] = 0.f; }
    __syncthreads();
    const int c = (tid & 31) * 4;  // blockDim & grid-stride are multiples of 32 -> column fixed per thread
    const float4 sc = *reinterpret_cast<const float4*>(scale + c);
    const float4 sh = *reinterpret_cast<const float4*>(shift + c);
    const long long stride = (long long)gridDim.x * blockDim.x;
    float ls[4] = {}, lq[4] = {};
    for (long long i = (long long)blockIdx.x * blockDim.x + tid; i < n4; i += stride) {
        float4 v = *reinterpret_cast<const float4*>(z + i * 4);
        float t;
        t = fmaxf(v.x * sc.x + sh.x, 0.f); ls[0] += t; lq[0] += t * t;
        t = fmaxf(v.y * sc.y + sh.y, 0.f); ls[1] += t; lq[1] += t * t;
        t = fmaxf(v.z * sc.z + sh.z, 0.f); ls[2] += t; lq[2] += t * t;
        t = fmaxf(v.w * sc.w + sh.w, 0.f); ls[3] += t; lq[3] += t * t;
    }
    atomicAdd(&redS[c + 0], ls[0]);
    atomicAdd(&redS[c + 1], ls[1]);
    atomicAdd(&redS[c + 2], ls[2]);
    atomicAdd(&redS[c + 3], ls[3]);
    atomicAdd(&redQ[c + 0], lq[0]);
    atomicAdd(&redQ[c + 1], lq[1]);
    atomicAdd(&redQ[c + 2], lq[2]);
    atomicAdd(&redQ[c + 3], lq[3]);
    __syncthreads();
    if (tid < D) {
        atomicAdd(&gsum[tid], redS[tid]);
        atomicAdd(&gsq[tid], redQ[tid]);
    }
}

// ---------------------------------------------------------------- h = relu(bn3(relu(bn2(z)))), in place
__global__ void final_apply(float* __restrict__ z,
                            const float* __restrict__ s2, const float* __restrict__ f2,
                            const float* __restrict__ s3, const float* __restrict__ f3,
                            long long n4) {
    const int tid = threadIdx.x;
    const int c = (tid & 31) * 4;
    const float4 a2 = *reinterpret_cast<const float4*>(s2 + c);
    const float4 b2 = *reinterpret_cast<const float4*>(f2 + c);
    const float4 a3 = *reinterpret_cast<const float4*>(s3 + c);
    const float4 b3 = *reinterpret_cast<const float4*>(f3 + c);
    const long long stride = (long long)gridDim.x * blockDim.x;
    for (long long i = (long long)blockIdx.x * blockDim.x + tid; i < n4; i += stride) {
        float4 v = *reinterpret_cast<const float4*>(z + i * 4);
        v.x = fmaxf(fmaxf(v.x * a2.x + b2.x, 0.f) * a3.x + b3.x, 0.f);
        v.y = fmaxf(fmaxf(v.y * a2.y + b2.y, 0.f) * a3.y + b3.y, 0.f);
        v.z = fmaxf(fmaxf(v.z * a2.z + b2.z, 0.f) * a3.z + b3.z, 0.f);
        v.w = fmaxf(fmaxf(v.w * a2.w + b2.w, 0.f) * a3.w + b3.w, 0.f);
        *reinterpret_cast<float4*>(z + i * 4) = v;
    }
}

// ---------------------------------------------------------------- segment-sum pooling (graph_id sorted): run-length local acc + atomic flush
__global__ void pool_sum(const float* __restrict__ h, const int* __restrict__ gid,
                         float* __restrict__ pooled, int nRows) {
    const int tid = threadIdx.x;
    const int c = tid & 127;
    const int rsub = tid >> 7;  // 0 or 1
    const long long row0 = (long long)blockIdx.x * 64;
    float acc = 0.f;
    int cur = -1;
    for (int r = rsub; r < 64; r += 2) {
        long long row = row0 + r;
        if (row >= nRows) break;
        int g = gid[row];
        if (g != cur) {
            if (cur >= 0) atomicAdd(&pooled[(long long)cur * D + c], acc);
            cur = g;
            acc = 0.f;
        }
        acc += h[row * D + c];
    }
    if (cur >= 0) atomicAdd(&pooled[(long long)cur * D + c], acc);
}

// ---------------------------------------------------------------- prediction heads: score = sum_i pooled_i @ pW_i + pb_i
__global__ void pred_heads(const float* __restrict__ pooled0, const float* __restrict__ pooledL,
                           const float* __restrict__ pW, const float* __restrict__ pb,
                           float* __restrict__ score) {
    int idx = blockIdx.x * blockDim.x + threadIdx.x;
    if (idx >= G * OUT) return;
    int g = idx >> 6, o = idx & 63;
    float acc = 0.f;
    for (int i = 0; i <= L; ++i) {
        const float* p = (i == 0) ? (pooled0 + (long long)g * D)
                                  : (pooledL + (long long)(i - 1) * G * D + (long long)g * D);
        const float* w = pW + (long long)i * D * OUT + o;
        float s = 0.f;
#pragma unroll 4
        for (int k = 0; k < D; ++k) s += p[k] * w[(long long)k * OUT];
        acc += s + pb[i * OUT + o];
    }
    score[idx] = acc;
}

// ----------------------------------------------------------------
extern "C" void kernel_launch(void* const* d_in, const int* in_sizes, int n_in,
                              void* d_out, int out_size, void* d_ws, size_t ws_size,
                              hipStream_t stream) {
    const float* h0  = (const float*)d_in[0];
    const int*   src = (const int*)d_in[2];
    const int*   dst = (const int*)d_in[3];
    const int*   gid = (const int*)d_in[4];
    const float* eps = (const float*)d_in[5];
    const float* W1  = (const float*)d_in[6];
    const float* b1  = (const float*)d_in[7];
    const float* W2  = (const float*)d_in[8];
    const float* b2  = (const float*)d_in[9];
    const float* bn1g = (const float*)d_in[10];
    const float* bn1b = (const float*)d_in[11];
    const float* bn2g = (const float*)d_in[12];
    const float* bn2b = (const float*)d_in[13];
    const float* bn3g = (const float*)d_in[14];
    const float* bn3b = (const float*)d_in[15];
    const float* pW  = (const float*)d_in[16];
    const float* pb  = (const float*)d_in[17];

    const int N = in_sizes[0] / D;
    const int E = in_sizes[2];
    const size_t nd = (size_t)N * D;

    float* bufX = (float*)d_ws;
    float* bufY = bufX + nd;
    float* bufZ = bufY + nd;
    float* gsum = bufZ + nd;
    float* gsq  = gsum + D;
    float* s1 = gsq + D;  float* f1 = s1 + D;
    float* s2 = f1 + D;   float* f2 = s2 + D;
    float* s3 = f2 + D;   float* f3 = s3 + D;
    float* pooled0 = f3 + D;

    float* score = (float*)d_out;
    float* pooledOut = score + G * OUT;  // pooled[1..4], each G*D

    hipMemsetAsync(d_out, 0, (size_t)out_size * sizeof(float), stream);
    hipMemsetAsync(pooled0, 0, (size_t)G * D * sizeof(float), stream);

    const int poolGrid = (N + 63) / 64;
    const int ggrid = (N + 63) / 64;
    const int sgrid = (int)(((long long)E * 32 + 255) / 256);
    const long long n4 = (long long)N * (D / 4);
    const float invN = 1.0f / (float)N;

    pool_sum<<<poolGrid, 256, 0, stream>>>(h0, gid, pooled0, N);

    const float* hin = h0;
    float* cur = bufX;   // agg -> z2 -> h for this layer
    float* nxt = bufZ;

    for (int i = 0; i < L; ++i) {
        hipMemsetAsync(cur, 0, nd * sizeof(float), stream);
        scatter_agg<<<sgrid, 256, 0, stream>>>(hin, src, dst, cur, E);

        hipMemsetAsync(gsum, 0, 2 * D * sizeof(float), stream);
        gemm128<0><<<ggrid, 512, 0, stream>>>(hin, cur, nullptr, nullptr, eps + i,
                                              W1 + (size_t)i * D * D, b1 + (size_t)i * D,
                                              bufY, gsum, gsq, N);
        bn_finalize<<<1, D, 0, stream>>>(gsum, gsq, bn1g + i * D, bn1b + i * D, invN, s1, f1);

        hipMemsetAsync(gsum, 0, 2 * D * sizeof(float), stream);
        gemm128<1><<<ggrid, 512, 0, stream>>>(bufY, nullptr, s1, f1, nullptr,
                                              W2 + (size_t)i * D * D, b2 + (size_t)i * D,
                                              cur, gsum, gsq, N);
        bn_finalize<<<1, D, 0, stream>>>(gsum, gsq, bn2g + i * D, bn2b + i * D, invN, s2, f2);

        hipMemsetAsync(gsum, 0, 2 * D * sizeof(float), stream);
        relu_bn_stats<<<2048, 256, 0, stream>>>(cur, s2, f2, gsum, gsq, n4);
        bn_finalize<<<1, D, 0, stream>>>(gsum, gsq, bn3g + i * D, bn3b + i * D, invN, s3, f3);

        final_apply<<<2048, 256, 0, stream>>>(cur, s2, f2, s3, f3, n4);

        pool_sum<<<poolGrid, 256, 0, stream>>>(cur, gid, pooledOut + (size_t)i * G * D, N);

        hin = cur;
        float* t = cur; cur = nxt; nxt = t;
    }

    pred_heads<<<(G * OUT + 255) / 256, 256, 0, stream>>>(pooled0, pooledOut, pW, pb, score);
}

// Round 2
// 2064.948 us; speedup vs baseline: 5.9231x; 5.9231x over previous
//
#include <hip/hip_runtime.h>

constexpr int D   = 128;
constexpr int G   = 64;
constexpr int OUT = 64;
constexpr int L   = 4;
#define BN_EPS 1e-5f

// ================================================================ CSR build
__global__ void edge_hist(const int* __restrict__ dst, int* __restrict__ deg, int nE) {
    int e = blockIdx.x * blockDim.x + threadIdx.x;
    if (e < nE) atomicAdd(&deg[dst[e]], 1);
}

// block-level exclusive scan: 256 threads x 8 elements = 2048/block
constexpr int SCAN_B = 256;
constexpr int SCAN_E = 8;
constexpr int SCAN_CHUNK = SCAN_B * SCAN_E;

__global__ __launch_bounds__(SCAN_B) void scan_pass1(const int* __restrict__ deg,
                                                     int* __restrict__ rowptr,
                                                     int* __restrict__ bsum, int n) {
    __shared__ int sm[SCAN_B];
    const int tid = threadIdx.x;
    const int base = blockIdx.x * SCAN_CHUNK + tid * SCAN_E;
    int v[SCAN_E];
    int s = 0;
#pragma unroll
    for (int j = 0; j < SCAN_E; ++j) {
        v[j] = (base + j < n) ? deg[base + j] : 0;
        s += v[j];
    }
    sm[tid] = s;
    __syncthreads();
    for (int off = 1; off < SCAN_B; off <<= 1) {
        int t = (tid >= off) ? sm[tid - off] : 0;
        __syncthreads();
        sm[tid] += t;
        __syncthreads();
    }
    int run = sm[tid] - s;  // exclusive prefix within block
#pragma unroll
    for (int j = 0; j < SCAN_E; ++j) {
        if (base + j < n) rowptr[base + j] = run;
        run += v[j];
    }
    if (tid == SCAN_B - 1) bsum[blockIdx.x] = sm[SCAN_B - 1];
}

__global__ void scan_pass2(int* __restrict__ bsum, int nb) {
    if (threadIdx.x == 0 && blockIdx.x == 0) {
        int t = 0;
        for (int i = 0; i < nb; ++i) {
            int s = bsum[i];
            bsum[i] = t;
            t += s;
        }
    }
}

__global__ __launch_bounds__(SCAN_B) void scan_pass3(int* __restrict__ rowptr,
                                                     const int* __restrict__ bsum,
                                                     int n, int total) {
    const int add = bsum[blockIdx.x];
    const int base = blockIdx.x * SCAN_CHUNK + threadIdx.x * SCAN_E;
#pragma unroll
    for (int j = 0; j < SCAN_E; ++j)
        if (base + j < n) rowptr[base + j] += add;
    if (blockIdx.x == 0 && threadIdx.x == 0) rowptr[n] = total;
}

__global__ void csr_fill(const int* __restrict__ src, const int* __restrict__ dst,
                         int* __restrict__ cursor, int* __restrict__ esrc, int nE) {
    int e = blockIdx.x * blockDim.x + threadIdx.x;
    if (e < nE) {
        int pos = atomicAdd(&cursor[dst[e]], 1);
        esrc[pos] = src[e];
    }
}

// ================================================================ aggregation (gather) + GIN combine
// x[r] = (1+eps)*h[r] + sum_{j in in-edges(r)} h[esrc[j]]
__global__ __launch_bounds__(256) void agg_gather(const float* __restrict__ h,
                                                  const int* __restrict__ rowptr,
                                                  const int* __restrict__ esrc,
                                                  const float* __restrict__ epsP,
                                                  float* __restrict__ x, int nRows) {
    const int r = blockIdx.x * 8 + (threadIdx.x >> 5);
    if (r >= nRows) return;
    const int c = (threadIdx.x & 31) * 4;
    const int beg = rowptr[r], end = rowptr[r + 1];
    const float ep = 1.0f + epsP[0];
    float4 a = *reinterpret_cast<const float4*>(h + (long long)r * D + c);
    float4 acc;
    acc.x = ep * a.x; acc.y = ep * a.y; acc.z = ep * a.z; acc.w = ep * a.w;
    for (int j = beg; j < end; ++j) {
        int s = esrc[j];
        float4 v = *reinterpret_cast<const float4*>(h + (long long)s * D + c);
        acc.x += v.x; acc.y += v.y; acc.z += v.z; acc.w += v.w;
    }
    *reinterpret_cast<float4*>(x + (long long)r * D + c) = acc;
}

// ================================================================ GEMM (N x 128) @ (128 x 128) + bias, fused input transform + BN-stat epilogue
// MODE 1: A(row,k) = relu(in0*scale[k] + shift[k])   (BN+ReLU on the fly)
// MODE 2: A(row,k) = in0                             (plain)
template <int MODE>
__global__ __launch_bounds__(512) void gemm128(
    const float* __restrict__ in0,
    const float* __restrict__ scale, const float* __restrict__ shift,
    const float* __restrict__ W, const float* __restrict__ bias,
    float* __restrict__ out, float* __restrict__ gsum, float* __restrict__ gsq,
    int nRows) {
    __shared__ float wL[D * D];          // 64 KB
    __shared__ float aL[64][D + 1];      // 33 KB
    __shared__ float redS[D];
    __shared__ float redQ[D];

    const int tid = threadIdx.x;
    const long long row0 = (long long)blockIdx.x * 64;

    for (int i = tid * 4; i < D * D; i += 512 * 4)
        *reinterpret_cast<float4*>(&wL[i]) = *reinterpret_cast<const float4*>(&W[i]);

    for (int i = tid; i < 64 * 32; i += 512) {
        int r = i >> 5, q = i & 31;
        long long row = row0 + r;
        float4 v = make_float4(0.f, 0.f, 0.f, 0.f);
        if (row < nRows) {
            v = *reinterpret_cast<const float4*>(in0 + row * D + q * 4);
            if (MODE == 1) {
                int c = q * 4;
                v.x = fmaxf(v.x * scale[c + 0] + shift[c + 0], 0.f);
                v.y = fmaxf(v.y * scale[c + 1] + shift[c + 1], 0.f);
                v.z = fmaxf(v.z * scale[c + 2] + shift[c + 2], 0.f);
                v.w = fmaxf(v.w * scale[c + 3] + shift[c + 3], 0.f);
            }
        }
        aL[r][q * 4 + 0] = v.x;
        aL[r][q * 4 + 1] = v.y;
        aL[r][q * 4 + 2] = v.z;
        aL[r][q * 4 + 3] = v.w;
    }
    if (tid < D) { redS[tid] = 0.f; redQ[tid] = 0.f; }
    __syncthreads();

    const int ct = tid & 31, rt = tid >> 5;
    const int c0 = ct * 4, r0 = rt * 4;
    float acc[4][4] = {};
#pragma unroll 4
    for (int k = 0; k < D; ++k) {
        float4 wv = *reinterpret_cast<const float4*>(&wL[k * D + c0]);
        float a0 = aL[r0 + 0][k];
        float a1 = aL[r0 + 1][k];
        float a2 = aL[r0 + 2][k];
        float a3 = aL[r0 + 3][k];
        acc[0][0] += a0 * wv.x; acc[0][1] += a0 * wv.y; acc[0][2] += a0 * wv.z; acc[0][3] += a0 * wv.w;
        acc[1][0] += a1 * wv.x; acc[1][1] += a1 * wv.y; acc[1][2] += a1 * wv.z; acc[1][3] += a1 * wv.w;
        acc[2][0] += a2 * wv.x; acc[2][1] += a2 * wv.y; acc[2][2] += a2 * wv.z; acc[2][3] += a2 * wv.w;
        acc[3][0] += a3 * wv.x; acc[3][1] += a3 * wv.y; acc[3][2] += a3 * wv.z; acc[3][3] += a3 * wv.w;
    }

    const float4 bv = *reinterpret_cast<const float4*>(bias + c0);
    float lsum[4] = {}, lsq[4] = {};
#pragma unroll
    for (int i = 0; i < 4; ++i) {
        long long row = row0 + r0 + i;
        if (row < nRows) {
            float4 o;
            o.x = acc[i][0] + bv.x;
            o.y = acc[i][1] + bv.y;
            o.z = acc[i][2] + bv.z;
            o.w = acc[i][3] + bv.w;
            *reinterpret_cast<float4*>(out + row * D + c0) = o;
            lsum[0] += o.x; lsq[0] += o.x * o.x;
            lsum[1] += o.y; lsq[1] += o.y * o.y;
            lsum[2] += o.z; lsq[2] += o.z * o.z;
            lsum[3] += o.w; lsq[3] += o.w * o.w;
        }
    }
    atomicAdd(&redS[c0 + 0], lsum[0]);
    atomicAdd(&redS[c0 + 1], lsum[1]);
    atomicAdd(&redS[c0 + 2], lsum[2]);
    atomicAdd(&redS[c0 + 3], lsum[3]);
    atomicAdd(&redQ[c0 + 0], lsq[0]);
    atomicAdd(&redQ[c0 + 1], lsq[1]);
    atomicAdd(&redQ[c0 + 2], lsq[2]);
    atomicAdd(&redQ[c0 + 3], lsq[3]);
    __syncthreads();
    if (tid < D) {
        atomicAdd(&gsum[tid], redS[tid]);
        atomicAdd(&gsq[tid], redQ[tid]);
    }
}

// ================================================================ BN finalize
__global__ void bn_finalize(const float* __restrict__ gsum, const float* __restrict__ gsq,
                            const float* __restrict__ g, const float* __restrict__ b,
                            float invN, float* __restrict__ scale, float* __restrict__ shift) {
    int c = threadIdx.x;
    float m = gsum[c] * invN;
    float v = gsq[c] * invN - m * m;
    float inv = rsqrtf(v + BN_EPS);
    float sc = g[c] * inv;
    scale[c] = sc;
    shift[c] = b[c] - m * sc;
}

// ================================================================ stats of relu(bn2(z))
__global__ void relu_bn_stats(const float* __restrict__ z,
                              const float* __restrict__ scale, const float* __restrict__ shift,
                              float* __restrict__ gsum, float* __restrict__ gsq, long long n4) {
    __shared__ float redS[D], redQ[D];
    const int tid = threadIdx.x;
    if (tid < D) { redS[tid] = 0.f; redQ[tid] = 0.f; }
    __syncthreads();
    const int c = (tid & 31) * 4;
    const float4 sc = *reinterpret_cast<const float4*>(scale + c);
    const float4 sh = *reinterpret_cast<const float4*>(shift + c);
    const long long stride = (long long)gridDim.x * blockDim.x;
    float ls[4] = {}, lq[4] = {};
    for (long long i = (long long)blockIdx.x * blockDim.x + tid; i < n4; i += stride) {
        float4 v = *reinterpret_cast<const float4*>(z + i * 4);
        float t;
        t = fmaxf(v.x * sc.x + sh.x, 0.f); ls[0] += t; lq[0] += t * t;
        t = fmaxf(v.y * sc.y + sh.y, 0.f); ls[1] += t; lq[1] += t * t;
        t = fmaxf(v.z * sc.z + sh.z, 0.f); ls[2] += t; lq[2] += t * t;
        t = fmaxf(v.w * sc.w + sh.w, 0.f); ls[3] += t; lq[3] += t * t;
    }
    atomicAdd(&redS[c + 0], ls[0]);
    atomicAdd(&redS[c + 1], ls[1]);
    atomicAdd(&redS[c + 2], ls[2]);
    atomicAdd(&redS[c + 3], ls[3]);
    atomicAdd(&redQ[c + 0], lq[0]);
    atomicAdd(&redQ[c + 1], lq[1]);
    atomicAdd(&redQ[c + 2], lq[2]);
    atomicAdd(&redQ[c + 3], lq[3]);
    __syncthreads();
    if (tid < D) {
        atomicAdd(&gsum[tid], redS[tid]);
        atomicAdd(&gsq[tid], redQ[tid]);
    }
}

// ================================================================ h = relu(bn3(relu(bn2(z)))) in place + graph pooling
__global__ __launch_bounds__(256) void final_apply_pool(
    float* __restrict__ z, const int* __restrict__ gid,
    const float* __restrict__ s2, const float* __restrict__ f2,
    const float* __restrict__ s3, const float* __restrict__ f3,
    float* __restrict__ pooled, int nRows) {
    const int tid = threadIdx.x;
    const int c = tid & 127;
    const int rsub = tid >> 7;
    const long long row0 = (long long)blockIdx.x * 64;
    const float a2 = s2[c], b2 = f2[c], a3 = s3[c], b3 = f3[c];
    float acc = 0.f;
    int cur = -1;
    for (int r = rsub; r < 64; r += 2) {
        long long row = row0 + r;
        if (row >= nRows) break;
        float v = z[row * D + c];
        v = fmaxf(fmaxf(v * a2 + b2, 0.f) * a3 + b3, 0.f);
        z[row * D + c] = v;
        int g = gid[row];
        if (g != cur) {
            if (cur >= 0) atomicAdd(&pooled[(long long)cur * D + c], acc);
            cur = g;
            acc = 0.f;
        }
        acc += v;
    }
    if (cur >= 0) atomicAdd(&pooled[(long long)cur * D + c], acc);
}

// ================================================================ plain pooling (for h0)
__global__ __launch_bounds__(256) void pool_sum(const float* __restrict__ h, const int* __restrict__ gid,
                                                float* __restrict__ pooled, int nRows) {
    const int tid = threadIdx.x;
    const int c = tid & 127;
    const int rsub = tid >> 7;
    const long long row0 = (long long)blockIdx.x * 64;
    float acc = 0.f;
    int cur = -1;
    for (int r = rsub; r < 64; r += 2) {
        long long row = row0 + r;
        if (row >= nRows) break;
        int g = gid[row];
        if (g != cur) {
            if (cur >= 0) atomicAdd(&pooled[(long long)cur * D + c], acc);
            cur = g;
            acc = 0.f;
        }
        acc += h[row * D + c];
    }
    if (cur >= 0) atomicAdd(&pooled[(long long)cur * D + c], acc);
}

// ================================================================ prediction heads
__global__ void pred_heads(const float* __restrict__ pooled0, const float* __restrict__ pooledL,
                           const float* __restrict__ pW, const float* __restrict__ pb,
                           float* __restrict__ score) {
    int idx = blockIdx.x * blockDim.x + threadIdx.x;
    if (idx >= G * OUT) return;
    int g = idx >> 6, o = idx & 63;
    float acc = 0.f;
    for (int i = 0; i <= L; ++i) {
        const float* p = (i == 0) ? (pooled0 + (long long)g * D)
                                  : (pooledL + (long long)(i - 1) * G * D + (long long)g * D);
        const float* w = pW + (long long)i * D * OUT + o;
        float s = 0.f;
#pragma unroll 4
        for (int k = 0; k < D; ++k) s += p[k] * w[(long long)k * OUT];
        acc += s + pb[i * OUT + o];
    }
    score[idx] = acc;
}

// ================================================================
extern "C" void kernel_launch(void* const* d_in, const int* in_sizes, int n_in,
                              void* d_out, int out_size, void* d_ws, size_t ws_size,
                              hipStream_t stream) {
    const float* h0  = (const float*)d_in[0];
    const int*   src = (const int*)d_in[2];
    const int*   dst = (const int*)d_in[3];
    const int*   gid = (const int*)d_in[4];
    const float* eps = (const float*)d_in[5];
    const float* W1  = (const float*)d_in[6];
    const float* b1  = (const float*)d_in[7];
    const float* W2  = (const float*)d_in[8];
    const float* b2  = (const float*)d_in[9];
    const float* bn1g = (const float*)d_in[10];
    const float* bn1b = (const float*)d_in[11];
    const float* bn2g = (const float*)d_in[12];
    const float* bn2b = (const float*)d_in[13];
    const float* bn3g = (const float*)d_in[14];
    const float* bn3b = (const float*)d_in[15];
    const float* pW  = (const float*)d_in[16];
    const float* pb  = (const float*)d_in[17];

    const int N = in_sizes[0] / D;
    const int E = in_sizes[2];
    const size_t nd = (size_t)N * D;

    // ---- workspace layout (floats then ints), ~110 MB total
    float* bufH = (float*)d_ws;      // y / z / h chain (in-place)
    float* bufX = bufH + nd;         // x per layer
    float* gsum = bufX + nd;
    float* gsq  = gsum + D;
    float* s1 = gsq + D;  float* f1 = s1 + D;
    float* s2 = f1 + D;   float* f2 = s2 + D;
    float* s3 = f2 + D;   float* f3 = s3 + D;
    float* pooled0 = f3 + D;         // G*D
    int* deg    = (int*)(pooled0 + (size_t)G * D);
    int* rowptr = deg + N;           // N+1
    int* cursor = rowptr + (N + 1);
    int* esrc   = cursor + N;        // E
    int* bsum   = esrc + E;          // scan block sums

    float* score = (float*)d_out;
    float* pooledOut = score + G * OUT;  // pooled[1..4], each G*D

    const int nb = (N + SCAN_CHUNK - 1) / SCAN_CHUNK;
    const int egrid = (E + 255) / 256;
    const int poolGrid = (N + 63) / 64;
    const int ggrid = (N + 63) / 64;
    const int agrid = (N + 7) / 8;
    const long long n4 = (long long)N * (D / 4);
    const float invN = 1.0f / (float)N;

    // ---- CSR build (once per call)
    hipMemsetAsync(deg, 0, (size_t)N * sizeof(int), stream);
    edge_hist<<<egrid, 256, 0, stream>>>(dst, deg, E);
    scan_pass1<<<nb, SCAN_B, 0, stream>>>(deg, rowptr, bsum, N);
    scan_pass2<<<1, 64, 0, stream>>>(bsum, nb);
    scan_pass3<<<nb, SCAN_B, 0, stream>>>(rowptr, bsum, N, E);
    hipMemcpyAsync(cursor, rowptr, (size_t)N * sizeof(int), hipMemcpyDeviceToDevice, stream);
    csr_fill<<<egrid, 256, 0, stream>>>(src, dst, cursor, esrc, E);

    // ---- outputs / pooled zero
    hipMemsetAsync(d_out, 0, (size_t)out_size * sizeof(float), stream);
    hipMemsetAsync(pooled0, 0, (size_t)G * D * sizeof(float), stream);

    pool_sum<<<poolGrid, 256, 0, stream>>>(h0, gid, pooled0, N);

    const float* hin = h0;
    for (int i = 0; i < L; ++i) {
        // x = (1+eps)*h + gather-sum
        agg_gather<<<agrid, 256, 0, stream>>>(hin, rowptr, esrc, eps + i, bufX, N);

        // y = x @ W1 + b1  (+ BN1 stats)
        hipMemsetAsync(gsum, 0, 2 * D * sizeof(float), stream);
        gemm128<2><<<ggrid, 512, 0, stream>>>(bufX, nullptr, nullptr,
                                              W1 + (size_t)i * D * D, b1 + (size_t)i * D,
                                              bufH, gsum, gsq, N);
        bn_finalize<<<1, D, 0, stream>>>(gsum, gsq, bn1g + i * D, bn1b + i * D, invN, s1, f1);

        // z = relu(bn1(y)) @ W2 + b2  (+ BN2 stats), in place on bufH
        hipMemsetAsync(gsum, 0, 2 * D * sizeof(float), stream);
        gemm128<1><<<ggrid, 512, 0, stream>>>(bufH, s1, f1,
                                              W2 + (size_t)i * D * D, b2 + (size_t)i * D,
                                              bufH, gsum, gsq, N);
        bn_finalize<<<1, D, 0, stream>>>(gsum, gsq, bn2g + i * D, bn2b + i * D, invN, s2, f2);

        // stats of relu(bn2(z)) -> BN3
        hipMemsetAsync(gsum, 0, 2 * D * sizeof(float), stream);
        relu_bn_stats<<<2048, 256, 0, stream>>>(bufH, s2, f2, gsum, gsq, n4);
        bn_finalize<<<1, D, 0, stream>>>(gsum, gsq, bn3g + i * D, bn3b + i * D, invN, s3, f3);

        // h = relu(bn3(relu(bn2(z)))) in place + pooling
        final_apply_pool<<<poolGrid, 256, 0, stream>>>(bufH, gid, s2, f2, s3, f3,
                                                       pooledOut + (size_t)i * G * D, N);
        hin = bufH;
    }

    pred_heads<<<(G * OUT + 255) / 256, 256, 0, stream>>>(pooled0, pooledOut, pW, pb, score);
}

// Round 3
// 1651.966 us; speedup vs baseline: 7.4038x; 1.2500x over previous
//
#include <hip/hip_runtime.h>

constexpr int D   = 128;
constexpr int G   = 64;
constexpr int OUT = 64;
constexpr int L   = 4;
#define BN_EPS 1e-5f

typedef __attribute__((ext_vector_type(8))) short bf16x8;
typedef __attribute__((ext_vector_type(4))) short short4v;
typedef __attribute__((ext_vector_type(4))) float f32x4;

__device__ inline unsigned short f2bf(float f) {
    union { float f; unsigned int u; } x; x.f = f;
    unsigned int r = x.u + 0x7FFF + ((x.u >> 16) & 1);   // RNE
    return (unsigned short)(r >> 16);
}

// ================================================================ CSR build
__global__ void edge_hist(const int* __restrict__ dst, int* __restrict__ deg, int nE) {
    int e = blockIdx.x * blockDim.x + threadIdx.x;
    if (e < nE) atomicAdd(&deg[dst[e]], 1);
}

constexpr int SCAN_B = 256;
constexpr int SCAN_E = 8;
constexpr int SCAN_CHUNK = SCAN_B * SCAN_E;

__global__ __launch_bounds__(SCAN_B) void scan_pass1(const int* __restrict__ deg,
                                                     int* __restrict__ rowptr,
                                                     int* __restrict__ bsum, int n) {
    __shared__ int sm[SCAN_B];
    const int tid = threadIdx.x;
    const int base = blockIdx.x * SCAN_CHUNK + tid * SCAN_E;
    int v[SCAN_E];
    int s = 0;
#pragma unroll
    for (int j = 0; j < SCAN_E; ++j) {
        v[j] = (base + j < n) ? deg[base + j] : 0;
        s += v[j];
    }
    sm[tid] = s;
    __syncthreads();
    for (int off = 1; off < SCAN_B; off <<= 1) {
        int t = (tid >= off) ? sm[tid - off] : 0;
        __syncthreads();
        sm[tid] += t;
        __syncthreads();
    }
    int run = sm[tid] - s;
#pragma unroll
    for (int j = 0; j < SCAN_E; ++j) {
        if (base + j < n) rowptr[base + j] = run;
        run += v[j];
    }
    if (tid == SCAN_B - 1) bsum[blockIdx.x] = sm[SCAN_B - 1];
}

__global__ void scan_pass2(int* __restrict__ bsum, int nb) {
    if (threadIdx.x == 0 && blockIdx.x == 0) {
        int t = 0;
        for (int i = 0; i < nb; ++i) {
            int s = bsum[i];
            bsum[i] = t;
            t += s;
        }
    }
}

__global__ __launch_bounds__(SCAN_B) void scan_pass3(int* __restrict__ rowptr,
                                                     const int* __restrict__ bsum,
                                                     int n, int total) {
    const int add = bsum[blockIdx.x];
    const int base = blockIdx.x * SCAN_CHUNK + threadIdx.x * SCAN_E;
#pragma unroll
    for (int j = 0; j < SCAN_E; ++j)
        if (base + j < n) rowptr[base + j] += add;
    if (blockIdx.x == 0 && threadIdx.x == 0) rowptr[n] = total;
}

__global__ void csr_fill(const int* __restrict__ src, const int* __restrict__ dst,
                         int* __restrict__ cursor, int* __restrict__ esrc, int nE) {
    int e = blockIdx.x * blockDim.x + threadIdx.x;
    if (e < nE) {
        int pos = atomicAdd(&cursor[dst[e]], 1);
        esrc[pos] = src[e];
    }
}

// ================================================================ weights -> bf16 transposed: Wt[mat][col][k]
__global__ void prep_weights(const float* __restrict__ W1, const float* __restrict__ W2,
                             unsigned short* __restrict__ Wt) {
    const int m = blockIdx.x;  // 0..2L-1
    const float* W = (m < L) ? (W1 + (size_t)m * D * D) : (W2 + (size_t)(m - L) * D * D);
    unsigned short* o = Wt + (size_t)m * D * D;
    for (int e = threadIdx.x * 4; e < D * D; e += 256 * 4) {
        float4 v = *reinterpret_cast<const float4*>(W + e);
        int k = e >> 7, c = e & 127;
        o[(c + 0) * D + k] = f2bf(v.x);
        o[(c + 1) * D + k] = f2bf(v.y);
        o[(c + 2) * D + k] = f2bf(v.z);
        o[(c + 3) * D + k] = f2bf(v.w);
    }
}

// ================================================================ aggregation (gather) + GIN combine
__global__ __launch_bounds__(256) void agg_gather(const float* __restrict__ h,
                                                  const int* __restrict__ rowptr,
                                                  const int* __restrict__ esrc,
                                                  const float* __restrict__ epsP,
                                                  float* __restrict__ x, int nRows) {
    const int r = blockIdx.x * 8 + (threadIdx.x >> 5);
    if (r >= nRows) return;
    const int c = (threadIdx.x & 31) * 4;
    const int beg = rowptr[r], end = rowptr[r + 1];
    const float ep = 1.0f + epsP[0];
    float4 a = *reinterpret_cast<const float4*>(h + (long long)r * D + c);
    float4 acc;
    acc.x = ep * a.x; acc.y = ep * a.y; acc.z = ep * a.z; acc.w = ep * a.w;
    for (int j = beg; j < end; ++j) {
        int s = esrc[j];
        float4 v = *reinterpret_cast<const float4*>(h + (long long)s * D + c);
        acc.x += v.x; acc.y += v.y; acc.z += v.z; acc.w += v.w;
    }
    *reinterpret_cast<float4*>(x + (long long)r * D + c) = acc;
}

// ================================================================ MFMA GEMM: out[N,128] = A[N,128] @ W[128,128] + bias, BN-stat epilogue
// MODE 1: A = relu(in0*scale + shift), MODE 2: A = in0
// Wt is bf16, pre-transposed [col][k]. LDS tiles XOR-swizzled (T2).
template <int MODE>
__global__ __launch_bounds__(256) void gemm_mfma(
    const float* __restrict__ in0,
    const float* __restrict__ scale, const float* __restrict__ shift,
    const unsigned short* __restrict__ Wt, const float* __restrict__ bias,
    float* __restrict__ out, float* __restrict__ gsum, float* __restrict__ gsq,
    int nRows) {
    __shared__ unsigned short wL[D * D];   // 32 KB, swizzled [col][k]
    __shared__ unsigned short aL[D * D];   // 32 KB, swizzled [row][k]
    __shared__ float redS[D], redQ[D];

    const int tid = threadIdx.x;
    const int row0 = blockIdx.x * 128;

    // stage Wt (bf16, linear from global, swizzled into LDS)
    for (int o = tid * 8; o < D * D; o += 256 * 8) {
        bf16x8 v = *reinterpret_cast<const bf16x8*>(Wt + o);
        int byte = o * 2;
        int r = byte >> 8;
        *reinterpret_cast<bf16x8*>((char*)wL + (byte ^ ((r & 7) << 4))) = v;
    }
    // stage A (fp32 -> transform -> bf16, swizzled)
#pragma unroll
    for (int it = 0; it < 16; ++it) {
        int e = (it * 256 + tid) * 4;
        int r = e >> 7, c = e & 127;
        int grow = row0 + r;
        float4 v = make_float4(0.f, 0.f, 0.f, 0.f);
        if (grow < nRows) {
            v = *reinterpret_cast<const float4*>(in0 + (size_t)grow * D + c);
            if (MODE == 1) {
                float4 sc = *reinterpret_cast<const float4*>(scale + c);
                float4 sh = *reinterpret_cast<const float4*>(shift + c);
                v.x = fmaxf(v.x * sc.x + sh.x, 0.f);
                v.y = fmaxf(v.y * sc.y + sh.y, 0.f);
                v.z = fmaxf(v.z * sc.z + sh.z, 0.f);
                v.w = fmaxf(v.w * sc.w + sh.w, 0.f);
            }
        }
        short4v b;
        b.x = (short)f2bf(v.x); b.y = (short)f2bf(v.y);
        b.z = (short)f2bf(v.z); b.w = (short)f2bf(v.w);
        int byte = r * 256 + c * 2;
        *reinterpret_cast<short4v*>((char*)aL + (byte ^ ((r & 7) << 4))) = b;
    }
    if (tid < D) { redS[tid] = 0.f; redQ[tid] = 0.f; }
    __syncthreads();

    const int lane = tid & 63;
    const int wv = tid >> 6;        // wave 0..3 owns rows [wv*32, wv*32+32)
    const int wrow = wv * 32;
    const int lr = lane & 15;
    const int lb = lane >> 4;

    f32x4 acc[2][8] = {};
#pragma unroll
    for (int kk = 0; kk < 4; ++kk) {
        bf16x8 aF[2];
#pragma unroll
        for (int m = 0; m < 2; ++m) {
            int r = wrow + m * 16 + lr;
            int byte = r * 256 + kk * 64 + lb * 16;
            aF[m] = *reinterpret_cast<const bf16x8*>((char*)aL + (byte ^ ((r & 7) << 4)));
        }
#pragma unroll
        for (int n = 0; n < 8; ++n) {
            int cr = n * 16 + lr;
            int byte = cr * 256 + kk * 64 + lb * 16;
            bf16x8 bF = *reinterpret_cast<const bf16x8*>((char*)wL + (byte ^ ((cr & 7) << 4)));
            acc[0][n] = __builtin_amdgcn_mfma_f32_16x16x32_bf16(aF[0], bF, acc[0][n], 0, 0, 0);
            acc[1][n] = __builtin_amdgcn_mfma_f32_16x16x32_bf16(aF[1], bF, acc[1][n], 0, 0, 0);
        }
    }

    // epilogue: C/D layout col=lane&15, row=(lane>>4)*4+reg  [m89/m91]
    float ls[8], lq[8];
#pragma unroll
    for (int n = 0; n < 8; ++n) { ls[n] = 0.f; lq[n] = 0.f; }
#pragma unroll
    for (int n = 0; n < 8; ++n) {
        int col = n * 16 + lr;
        float bv = bias[col];
#pragma unroll
        for (int m = 0; m < 2; ++m) {
#pragma unroll
            for (int j = 0; j < 4; ++j) {
                int row = row0 + wrow + m * 16 + lb * 4 + j;
                if (row < nRows) {
                    float o = acc[m][n][j] + bv;
                    out[(size_t)row * D + col] = o;
                    ls[n] += o; lq[n] += o * o;
                }
            }
        }
    }
#pragma unroll
    for (int n = 0; n < 8; ++n) {
        int col = n * 16 + lr;
        atomicAdd(&redS[col], ls[n]);
        atomicAdd(&redQ[col], lq[n]);
    }
    __syncthreads();
    if (tid < D) {
        atomicAdd(&gsum[tid], redS[tid]);
        atomicAdd(&gsq[tid], redQ[tid]);
    }
}

// ================================================================ BN finalize
__global__ void bn_finalize(const float* __restrict__ gsum, const float* __restrict__ gsq,
                            const float* __restrict__ g, const float* __restrict__ b,
                            float invN, float* __restrict__ scale, float* __restrict__ shift) {
    int c = threadIdx.x;
    float m = gsum[c] * invN;
    float v = gsq[c] * invN - m * m;
    float inv = rsqrtf(v + BN_EPS);
    float sc = g[c] * inv;
    scale[c] = sc;
    shift[c] = b[c] - m * sc;
}

// ================================================================ stats of relu(bn2(z))
__global__ void relu_bn_stats(const float* __restrict__ z,
                              const float* __restrict__ scale, const float* __restrict__ shift,
                              float* __restrict__ gsum, float* __restrict__ gsq, long long n4) {
    __shared__ float redS[D], redQ[D];
    const int tid = threadIdx.x;
    if (tid < D) { redS[tid] = 0.f; redQ[tid] = 0.f; }
    __syncthreads();
    const int c = (tid & 31) * 4;
    const float4 sc = *reinterpret_cast<const float4*>(scale + c);
    const float4 sh = *reinterpret_cast<const float4*>(shift + c);
    const long long stride = (long long)gridDim.x * blockDim.x;
    float ls[4] = {}, lq[4] = {};
    for (long long i = (long long)blockIdx.x * blockDim.x + tid; i < n4; i += stride) {
        float4 v = *reinterpret_cast<const float4*>(z + i * 4);
        float t;
        t = fmaxf(v.x * sc.x + sh.x, 0.f); ls[0] += t; lq[0] += t * t;
        t = fmaxf(v.y * sc.y + sh.y, 0.f); ls[1] += t; lq[1] += t * t;
        t = fmaxf(v.z * sc.z + sh.z, 0.f); ls[2] += t; lq[2] += t * t;
        t = fmaxf(v.w * sc.w + sh.w, 0.f); ls[3] += t; lq[3] += t * t;
    }
    atomicAdd(&redS[c + 0], ls[0]);
    atomicAdd(&redS[c + 1], ls[1]);
    atomicAdd(&redS[c + 2], ls[2]);
    atomicAdd(&redS[c + 3], ls[3]);
    atomicAdd(&redQ[c + 0], lq[0]);
    atomicAdd(&redQ[c + 1], lq[1]);
    atomicAdd(&redQ[c + 2], lq[2]);
    atomicAdd(&redQ[c + 3], lq[3]);
    __syncthreads();
    if (tid < D) {
        atomicAdd(&gsum[tid], redS[tid]);
        atomicAdd(&gsq[tid], redQ[tid]);
    }
}

// ================================================================ h = relu(bn3(relu(bn2(z)))) in place + pooling
__global__ __launch_bounds__(256) void final_apply_pool(
    float* __restrict__ z, const int* __restrict__ gid,
    const float* __restrict__ s2, const float* __restrict__ f2,
    const float* __restrict__ s3, const float* __restrict__ f3,
    float* __restrict__ pooled, int nRows) {
    const int tid = threadIdx.x;
    const int c = tid & 127;
    const int rsub = tid >> 7;
    const long long row0 = (long long)blockIdx.x * 64;
    const float a2 = s2[c], b2 = f2[c], a3 = s3[c], b3 = f3[c];
    float acc = 0.f;
    int cur = -1;
    for (int r = rsub; r < 64; r += 2) {
        long long row = row0 + r;
        if (row >= nRows) break;
        float v = z[row * D + c];
        v = fmaxf(fmaxf(v * a2 + b2, 0.f) * a3 + b3, 0.f);
        z[row * D + c] = v;
        int g = gid[row];
        if (g != cur) {
            if (cur >= 0) atomicAdd(&pooled[(long long)cur * D + c], acc);
            cur = g;
            acc = 0.f;
        }
        acc += v;
    }
    if (cur >= 0) atomicAdd(&pooled[(long long)cur * D + c], acc);
}

// ================================================================ plain pooling (h0)
__global__ __launch_bounds__(256) void pool_sum(const float* __restrict__ h, const int* __restrict__ gid,
                                                float* __restrict__ pooled, int nRows) {
    const int tid = threadIdx.x;
    const int c = tid & 127;
    const int rsub = tid >> 7;
    const long long row0 = (long long)blockIdx.x * 64;
    float acc = 0.f;
    int cur = -1;
    for (int r = rsub; r < 64; r += 2) {
        long long row = row0 + r;
        if (row >= nRows) break;
        int g = gid[row];
        if (g != cur) {
            if (cur >= 0) atomicAdd(&pooled[(long long)cur * D + c], acc);
            cur = g;
            acc = 0.f;
        }
        acc += h[row * D + c];
    }
    if (cur >= 0) atomicAdd(&pooled[(long long)cur * D + c], acc);
}

// ================================================================ prediction heads
__global__ void pred_heads(const float* __restrict__ pooled0, const float* __restrict__ pooledL,
                           const float* __restrict__ pW, const float* __restrict__ pb,
                           float* __restrict__ score) {
    int idx = blockIdx.x * blockDim.x + threadIdx.x;
    if (idx >= G * OUT) return;
    int g = idx >> 6, o = idx & 63;
    float acc = 0.f;
    for (int i = 0; i <= L; ++i) {
        const float* p = (i == 0) ? (pooled0 + (long long)g * D)
                                  : (pooledL + (long long)(i - 1) * G * D + (long long)g * D);
        const float* w = pW + (long long)i * D * OUT + o;
        float s = 0.f;
#pragma unroll 4
        for (int k = 0; k < D; ++k) s += p[k] * w[(long long)k * OUT];
        acc += s + pb[i * OUT + o];
    }
    score[idx] = acc;
}

// ================================================================
extern "C" void kernel_launch(void* const* d_in, const int* in_sizes, int n_in,
                              void* d_out, int out_size, void* d_ws, size_t ws_size,
                              hipStream_t stream) {
    const float* h0  = (const float*)d_in[0];
    const int*   src = (const int*)d_in[2];
    const int*   dst = (const int*)d_in[3];
    const int*   gid = (const int*)d_in[4];
    const float* eps = (const float*)d_in[5];
    const float* W1  = (const float*)d_in[6];
    const float* b1  = (const float*)d_in[7];
    const float* W2  = (const float*)d_in[8];
    const float* b2  = (const float*)d_in[9];
    const float* bn1g = (const float*)d_in[10];
    const float* bn1b = (const float*)d_in[11];
    const float* bn2g = (const float*)d_in[12];
    const float* bn2b = (const float*)d_in[13];
    const float* bn3g = (const float*)d_in[14];
    const float* bn3b = (const float*)d_in[15];
    const float* pW  = (const float*)d_in[16];
    const float* pb  = (const float*)d_in[17];

    const int N = in_sizes[0] / D;
    const int E = in_sizes[2];
    const size_t nd = (size_t)N * D;

    float* bufH = (float*)d_ws;      // y / z / h chain (in-place)
    float* bufX = bufH + nd;         // x per layer
    float* gsum = bufX + nd;
    float* gsq  = gsum + D;
    float* s1 = gsq + D;  float* f1 = s1 + D;
    float* s2 = f1 + D;   float* f2 = s2 + D;
    float* s3 = f2 + D;   float* f3 = s3 + D;
    float* pooled0 = f3 + D;         // G*D
    unsigned short* WtB = (unsigned short*)(pooled0 + (size_t)G * D);  // 2L*D*D bf16
    int* deg    = (int*)(WtB + (size_t)2 * L * D * D);
    int* rowptr = deg + N;           // N+1
    int* cursor = rowptr + (N + 1);
    int* esrc   = cursor + N;        // E
    int* bsum   = esrc + E;          // scan block sums

    float* score = (float*)d_out;
    float* pooledOut = score + G * OUT;  // pooled[1..4], each G*D

    const int nb = (N + SCAN_CHUNK - 1) / SCAN_CHUNK;
    const int egrid = (E + 255) / 256;
    const int poolGrid = (N + 63) / 64;
    const int ggrid = (N + 127) / 128;
    const int agrid = (N + 7) / 8;
    const long long n4 = (long long)N * (D / 4);
    const float invN = 1.0f / (float)N;

    // ---- CSR build + weight prep (once per call)
    hipMemsetAsync(deg, 0, (size_t)N * sizeof(int), stream);
    edge_hist<<<egrid, 256, 0, stream>>>(dst, deg, E);
    prep_weights<<<2 * L, 256, 0, stream>>>(W1, W2, WtB);
    scan_pass1<<<nb, SCAN_B, 0, stream>>>(deg, rowptr, bsum, N);
    scan_pass2<<<1, 64, 0, stream>>>(bsum, nb);
    scan_pass3<<<nb, SCAN_B, 0, stream>>>(rowptr, bsum, N, E);
    hipMemcpyAsync(cursor, rowptr, (size_t)N * sizeof(int), hipMemcpyDeviceToDevice, stream);
    csr_fill<<<egrid, 256, 0, stream>>>(src, dst, cursor, esrc, E);

    hipMemsetAsync(d_out, 0, (size_t)out_size * sizeof(float), stream);
    hipMemsetAsync(pooled0, 0, (size_t)G * D * sizeof(float), stream);

    pool_sum<<<poolGrid, 256, 0, stream>>>(h0, gid, pooled0, N);

    const float* hin = h0;
    for (int i = 0; i < L; ++i) {
        agg_gather<<<agrid, 256, 0, stream>>>(hin, rowptr, esrc, eps + i, bufX, N);

        // y = x @ W1 + b1  (+ BN1 stats)
        hipMemsetAsync(gsum, 0, 2 * D * sizeof(float), stream);
        gemm_mfma<2><<<ggrid, 256, 0, stream>>>(bufX, nullptr, nullptr,
                                                WtB + (size_t)i * D * D, b1 + (size_t)i * D,
                                                bufH, gsum, gsq, N);
        bn_finalize<<<1, D, 0, stream>>>(gsum, gsq, bn1g + i * D, bn1b + i * D, invN, s1, f1);

        // z = relu(bn1(y)) @ W2 + b2  (+ BN2 stats), in place on bufH
        hipMemsetAsync(gsum, 0, 2 * D * sizeof(float), stream);
        gemm_mfma<1><<<ggrid, 256, 0, stream>>>(bufH, s1, f1,
                                                WtB + (size_t)(L + i) * D * D, b2 + (size_t)i * D,
                                                bufH, gsum, gsq, N);
        bn_finalize<<<1, D, 0, stream>>>(gsum, gsq, bn2g + i * D, bn2b + i * D, invN, s2, f2);

        hipMemsetAsync(gsum, 0, 2 * D * sizeof(float), stream);
        relu_bn_stats<<<2048, 256, 0, stream>>>(bufH, s2, f2, gsum, gsq, n4);
        bn_finalize<<<1, D, 0, stream>>>(gsum, gsq, bn3g + i * D, bn3b + i * D, invN, s3, f3);

        final_apply_pool<<<poolGrid, 256, 0, stream>>>(bufH, gid, s2, f2, s3, f3,
                                                       pooledOut + (size_t)i * G * D, N);
        hin = bufH;
    }

    pred_heads<<<(G * OUT + 255) / 256, 256, 0, stream>>>(pooled0, pooledOut, pW, pb, score);
}

// Round 4
// 1315.842 us; speedup vs baseline: 9.2951x; 1.2554x over previous
//
#include <hip/hip_runtime.h>

constexpr int D   = 128;
constexpr int G   = 64;
constexpr int OUT = 64;
constexpr int L   = 4;
#define BN_EPS 1e-5f

typedef __attribute__((ext_vector_type(8))) short bf16x8;
typedef __attribute__((ext_vector_type(4))) short short4v;
typedef __attribute__((ext_vector_type(4))) float f32x4;
typedef unsigned short u16;

__device__ inline u16 f2bf(float f) {
    union { float f; unsigned u; } x; x.f = f;
    unsigned r = x.u + 0x7FFF + ((x.u >> 16) & 1);   // RNE
    return (u16)(r >> 16);
}
__device__ inline float bf2f(u16 u) {
    union { unsigned u; float f; } x; x.u = ((unsigned)u) << 16;
    return x.f;
}

// ================================================================ CSR build
__global__ void edge_hist(const int* __restrict__ dst, int* __restrict__ deg, int nE) {
    int e = blockIdx.x * blockDim.x + threadIdx.x;
    if (e < nE) atomicAdd(&deg[dst[e]], 1);
}

constexpr int SCAN_B = 256;
constexpr int SCAN_E = 8;
constexpr int SCAN_CHUNK = SCAN_B * SCAN_E;

__global__ __launch_bounds__(SCAN_B) void scan_pass1(const int* __restrict__ deg,
                                                     int* __restrict__ rowptr,
                                                     int* __restrict__ bsum, int n) {
    __shared__ int sm[SCAN_B];
    const int tid = threadIdx.x;
    const int base = blockIdx.x * SCAN_CHUNK + tid * SCAN_E;
    int v[SCAN_E];
    int s = 0;
#pragma unroll
    for (int j = 0; j < SCAN_E; ++j) {
        v[j] = (base + j < n) ? deg[base + j] : 0;
        s += v[j];
    }
    sm[tid] = s;
    __syncthreads();
    for (int off = 1; off < SCAN_B; off <<= 1) {
        int t = (tid >= off) ? sm[tid - off] : 0;
        __syncthreads();
        sm[tid] += t;
        __syncthreads();
    }
    int run = sm[tid] - s;
#pragma unroll
    for (int j = 0; j < SCAN_E; ++j) {
        if (base + j < n) rowptr[base + j] = run;
        run += v[j];
    }
    if (tid == SCAN_B - 1) bsum[blockIdx.x] = sm[SCAN_B - 1];
}

__global__ void scan_pass2(int* __restrict__ bsum, int nb) {
    if (threadIdx.x == 0 && blockIdx.x == 0) {
        int t = 0;
        for (int i = 0; i < nb; ++i) {
            int s = bsum[i];
            bsum[i] = t;
            t += s;
        }
    }
}

__global__ __launch_bounds__(SCAN_B) void scan_pass3(int* __restrict__ rowptr,
                                                     const int* __restrict__ bsum,
                                                     int n, int total) {
    const int add = bsum[blockIdx.x];
    const int base = blockIdx.x * SCAN_CHUNK + threadIdx.x * SCAN_E;
#pragma unroll
    for (int j = 0; j < SCAN_E; ++j)
        if (base + j < n) rowptr[base + j] += add;
    if (blockIdx.x == 0 && threadIdx.x == 0) rowptr[n] = total;
}

// bucketed fill: blocks sweep dst-range buckets so scattered esrc writes stay
// L2-resident (16K-node bucket -> ~0.9MB active window). Edges preloaded to regs.
__global__ __launch_bounds__(256) void csr_fill(const int* __restrict__ src, const int* __restrict__ dst,
                                                int* __restrict__ cursor, int* __restrict__ esrc,
                                                int nE, int nBuckets) {
    const int base = blockIdx.x * (256 * 8);
    int d[8], s[8];
#pragma unroll
    for (int j = 0; j < 8; ++j) {
        int e = base + j * 256 + threadIdx.x;
        d[j] = (e < nE) ? dst[e] : -1;
        s[j] = (e < nE) ? src[e] : 0;
    }
    for (int b = 0; b < nBuckets; ++b) {
        const int lo = b << 14, hi = lo + (1 << 14);
#pragma unroll
        for (int j = 0; j < 8; ++j) {
            if (d[j] >= lo && d[j] < hi) {
                int pos = atomicAdd(&cursor[d[j]], 1);
                esrc[pos] = s[j];
            }
        }
    }
}

// ================================================================ weights -> bf16 transposed: Wt[mat][col][k]
__global__ void prep_weights(const float* __restrict__ W1, const float* __restrict__ W2,
                             u16* __restrict__ Wt) {
    const int m = blockIdx.x;  // 0..2L-1
    const float* W = (m < L) ? (W1 + (size_t)m * D * D) : (W2 + (size_t)(m - L) * D * D);
    u16* o = Wt + (size_t)m * D * D;
    for (int e = threadIdx.x * 4; e < D * D; e += 256 * 4) {
        float4 v = *reinterpret_cast<const float4*>(W + e);
        int k = e >> 7, c = e & 127;
        o[(c + 0) * D + k] = f2bf(v.x);
        o[(c + 1) * D + k] = f2bf(v.y);
        o[(c + 2) * D + k] = f2bf(v.z);
        o[(c + 3) * D + k] = f2bf(v.w);
    }
}

// ================================================================ h0 -> bf16 + pool0
__global__ __launch_bounds__(256) void convert_pool(const float* __restrict__ h, const int* __restrict__ gid,
                                                    u16* __restrict__ hbf, float* __restrict__ pooled,
                                                    int nRows) {
    const int tid = threadIdx.x;
    const int c = tid & 127;
    const int rsub = tid >> 7;
    const long long row0 = (long long)blockIdx.x * 64;
    float acc = 0.f;
    int cur = -1;
    for (int r = rsub; r < 64; r += 2) {
        long long row = row0 + r;
        if (row >= nRows) break;
        float v = h[row * D + c];
        hbf[row * D + c] = f2bf(v);
        int g = gid[row];
        if (g != cur) {
            if (cur >= 0) atomicAdd(&pooled[(long long)cur * D + c], acc);
            cur = g;
            acc = 0.f;
        }
        acc += v;
    }
    if (cur >= 0) atomicAdd(&pooled[(long long)cur * D + c], acc);
}

// ================================================================ aggregation (bf16 gather) + GIN combine
__global__ __launch_bounds__(256) void agg_gather(const u16* __restrict__ hbf,
                                                  const int* __restrict__ rowptr,
                                                  const int* __restrict__ esrc,
                                                  const float* __restrict__ epsP,
                                                  u16* __restrict__ xbf, int nRows) {
    const int r = blockIdx.x * 8 + (threadIdx.x >> 5);
    if (r >= nRows) return;
    const int c = (threadIdx.x & 31) * 4;
    const int beg = rowptr[r], end = rowptr[r + 1];
    const float ep = 1.0f + epsP[0];
    short4v a = *reinterpret_cast<const short4v*>(hbf + (size_t)r * D + c);
    float acc[4];
#pragma unroll
    for (int j = 0; j < 4; ++j) acc[j] = ep * bf2f((u16)a[j]);
    for (int e = beg; e < end; ++e) {
        int s = esrc[e];
        short4v v = *reinterpret_cast<const short4v*>(hbf + (size_t)s * D + c);
#pragma unroll
        for (int j = 0; j < 4; ++j) acc[j] += bf2f((u16)v[j]);
    }
    short4v o;
#pragma unroll
    for (int j = 0; j < 4; ++j) o[j] = (short)f2bf(acc[j]);
    *reinterpret_cast<short4v*>(xbf + (size_t)r * D + c) = o;
}

// ================================================================ MFMA GEMM, bf16 A (128-tile), bf16 Wt [col][k], BN-stat epilogue
// MODE 1: A = relu(bn(in)) computed from prev raw stats; MODE 2: A = in.
// OUTBF: store output bf16 (else fp32). Stats accumulated on fp32 pre-round values.
template <int MODE, bool OUTBF>
__global__ __launch_bounds__(256) void gemm_mfma(
    const u16* __restrict__ A, const u16* __restrict__ Wt, const float* __restrict__ bias,
    const float* __restrict__ pSum, const float* __restrict__ pSq,
    const float* __restrict__ bng, const float* __restrict__ bnb, float invN,
    void* __restrict__ outP, float* __restrict__ gsum, float* __restrict__ gsq,
    int nRows) {
    __shared__ u16 wL[D * D];   // 32 KB swizzled [col][k]
    __shared__ u16 aL[D * D];   // 32 KB swizzled [row][k]
    __shared__ float redS[D], redQ[D];
    __shared__ float scL[D], shL[D];

    const int tid = threadIdx.x;
    const int row0 = blockIdx.x * 128;

    if (tid < D) {
        redS[tid] = 0.f; redQ[tid] = 0.f;
        if (MODE == 1) {
            float m = pSum[tid] * invN;
            float v = pSq[tid] * invN - m * m;
            float sc = bng[tid] * rsqrtf(v + BN_EPS);
            scL[tid] = sc;
            shL[tid] = bnb[tid] - m * sc;
        }
    }
    if (MODE == 1) __syncthreads();  // scL/shL ready before staging reads

    for (int o = tid * 8; o < D * D; o += 2048) {
        bf16x8 v = *reinterpret_cast<const bf16x8*>(Wt + o);
        int byte = o * 2, r = byte >> 8;
        *reinterpret_cast<bf16x8*>((char*)wL + (byte ^ ((r & 7) << 4))) = v;
    }
#pragma unroll
    for (int it = 0; it < 8; ++it) {
        int o = (it * 256 + tid) * 8;
        int r = o >> 7, c = o & 127;
        int grow = row0 + r;
        bf16x8 v = {};
        if (grow < nRows) {
            v = *reinterpret_cast<const bf16x8*>(A + (size_t)grow * D + c);
            if (MODE == 1) {
#pragma unroll
                for (int j = 0; j < 8; ++j) {
                    float t = fmaxf(bf2f((u16)v[j]) * scL[c + j] + shL[c + j], 0.f);
                    v[j] = (short)f2bf(t);
                }
            }
        }
        int byte = o * 2;
        *reinterpret_cast<bf16x8*>((char*)aL + (byte ^ ((r & 7) << 4))) = v;
    }
    __syncthreads();

    const int lane = tid & 63;
    const int wv = tid >> 6;
    const int wrow = wv * 32;
    const int lr = lane & 15;
    const int lb = lane >> 4;

    f32x4 acc[2][8] = {};
#pragma unroll
    for (int kk = 0; kk < 4; ++kk) {
        bf16x8 aF[2];
#pragma unroll
        for (int m = 0; m < 2; ++m) {
            int r = wrow + m * 16 + lr;
            int byte = r * 256 + kk * 64 + lb * 16;
            aF[m] = *reinterpret_cast<const bf16x8*>((char*)aL + (byte ^ ((r & 7) << 4)));
        }
#pragma unroll
        for (int n = 0; n < 8; ++n) {
            int cr = n * 16 + lr;
            int byte = cr * 256 + kk * 64 + lb * 16;
            bf16x8 bF = *reinterpret_cast<const bf16x8*>((char*)wL + (byte ^ ((cr & 7) << 4)));
            acc[0][n] = __builtin_amdgcn_mfma_f32_16x16x32_bf16(aF[0], bF, acc[0][n], 0, 0, 0);
            acc[1][n] = __builtin_amdgcn_mfma_f32_16x16x32_bf16(aF[1], bF, acc[1][n], 0, 0, 0);
        }
    }

    float ls[8], lq[8];
#pragma unroll
    for (int n = 0; n < 8; ++n) { ls[n] = 0.f; lq[n] = 0.f; }
#pragma unroll
    for (int n = 0; n < 8; ++n) {
        int col = n * 16 + lr;
        float bv = bias[col];
#pragma unroll
        for (int m = 0; m < 2; ++m) {
#pragma unroll
            for (int j = 0; j < 4; ++j) {
                int row = row0 + wrow + m * 16 + lb * 4 + j;
                if (row < nRows) {
                    float o = acc[m][n][j] + bv;
                    if (OUTBF)
                        ((u16*)outP)[(size_t)row * D + col] = f2bf(o);
                    else
                        ((float*)outP)[(size_t)row * D + col] = o;
                    ls[n] += o; lq[n] += o * o;
                }
            }
        }
    }
#pragma unroll
    for (int n = 0; n < 8; ++n) {
        int col = n * 16 + lr;
        atomicAdd(&redS[col], ls[n]);
        atomicAdd(&redQ[col], lq[n]);
    }
    __syncthreads();
    if (tid < D) {
        atomicAdd(&gsum[tid], redS[tid]);
        atomicAdd(&gsq[tid], redQ[tid]);
    }
}

// ================================================================ stats of relu(bn2(z)) ; scale/shift computed in-kernel
__global__ __launch_bounds__(256) void relu_bn_stats(const float* __restrict__ z,
                                                     const float* __restrict__ pSum, const float* __restrict__ pSq,
                                                     const float* __restrict__ bng, const float* __restrict__ bnb,
                                                     float invN,
                                                     float* __restrict__ gsum, float* __restrict__ gsq,
                                                     long long n4) {
    __shared__ float redS[D], redQ[D];
    const int tid = threadIdx.x;
    if (tid < D) { redS[tid] = 0.f; redQ[tid] = 0.f; }
    __syncthreads();
    const int c = (tid & 31) * 4;
    float sc[4], sh[4];
#pragma unroll
    for (int j = 0; j < 4; ++j) {
        float m = pSum[c + j] * invN;
        float v = pSq[c + j] * invN - m * m;
        float s = bng[c + j] * rsqrtf(v + BN_EPS);
        sc[j] = s;
        sh[j] = bnb[c + j] - m * s;
    }
    const long long stride = (long long)gridDim.x * blockDim.x;
    float ls[4] = {}, lq[4] = {};
    for (long long i = (long long)blockIdx.x * blockDim.x + tid; i < n4; i += stride) {
        float4 v = *reinterpret_cast<const float4*>(z + i * 4);
        float t;
        t = fmaxf(v.x * sc[0] + sh[0], 0.f); ls[0] += t; lq[0] += t * t;
        t = fmaxf(v.y * sc[1] + sh[1], 0.f); ls[1] += t; lq[1] += t * t;
        t = fmaxf(v.z * sc[2] + sh[2], 0.f); ls[2] += t; lq[2] += t * t;
        t = fmaxf(v.w * sc[3] + sh[3], 0.f); ls[3] += t; lq[3] += t * t;
    }
    atomicAdd(&redS[c + 0], ls[0]);
    atomicAdd(&redS[c + 1], ls[1]);
    atomicAdd(&redS[c + 2], ls[2]);
    atomicAdd(&redS[c + 3], ls[3]);
    atomicAdd(&redQ[c + 0], lq[0]);
    atomicAdd(&redQ[c + 1], lq[1]);
    atomicAdd(&redQ[c + 2], lq[2]);
    atomicAdd(&redQ[c + 3], lq[3]);
    __syncthreads();
    if (tid < D) {
        atomicAdd(&gsum[tid], redS[tid]);
        atomicAdd(&gsq[tid], redQ[tid]);
    }
}

// ================================================================ h = relu(bn3(relu(bn2(z)))) -> hbf (bf16) + pooling (fp32)
__global__ __launch_bounds__(256) void final_apply_pool(
    const float* __restrict__ z, const int* __restrict__ gid,
    const float* __restrict__ p1S, const float* __restrict__ p1Q,
    const float* __restrict__ g2, const float* __restrict__ b2v,
    const float* __restrict__ p2S, const float* __restrict__ p2Q,
    const float* __restrict__ g3, const float* __restrict__ b3v,
    float invN, u16* __restrict__ hbf, float* __restrict__ pooled, int nRows) {
    const int tid = threadIdx.x;
    const int c = tid & 127;
    const int rsub = tid >> 7;
    const long long row0 = (long long)blockIdx.x * 64;

    float m = p1S[c] * invN;
    float va = p1Q[c] * invN - m * m;
    float a2 = g2[c] * rsqrtf(va + BN_EPS);
    float f2v = b2v[c] - m * a2;
    m = p2S[c] * invN;
    va = p2Q[c] * invN - m * m;
    float a3 = g3[c] * rsqrtf(va + BN_EPS);
    float f3v = b3v[c] - m * a3;

    float acc = 0.f;
    int cur = -1;
    for (int r = rsub; r < 64; r += 2) {
        long long row = row0 + r;
        if (row >= nRows) break;
        float v = z[row * D + c];
        v = fmaxf(fmaxf(v * a2 + f2v, 0.f) * a3 + f3v, 0.f);
        hbf[row * D + c] = f2bf(v);
        int g = gid[row];
        if (g != cur) {
            if (cur >= 0) atomicAdd(&pooled[(long long)cur * D + c], acc);
            cur = g;
            acc = 0.f;
        }
        acc += v;
    }
    if (cur >= 0) atomicAdd(&pooled[(long long)cur * D + c], acc);
}

// ================================================================ prediction heads
__global__ void pred_heads(const float* __restrict__ pooled0, const float* __restrict__ pooledL,
                           const float* __restrict__ pW, const float* __restrict__ pb,
                           float* __restrict__ score) {
    int idx = blockIdx.x * blockDim.x + threadIdx.x;
    if (idx >= G * OUT) return;
    int g = idx >> 6, o = idx & 63;
    float acc = 0.f;
    for (int i = 0; i <= L; ++i) {
        const float* p = (i == 0) ? (pooled0 + (long long)g * D)
                                  : (pooledL + (long long)(i - 1) * G * D + (long long)g * D);
        const float* w = pW + (long long)i * D * OUT + o;
        float s = 0.f;
#pragma unroll 4
        for (int k = 0; k < D; ++k) s += p[k] * w[(long long)k * OUT];
        acc += s + pb[i * OUT + o];
    }
    score[idx] = acc;
}

// ================================================================
extern "C" void kernel_launch(void* const* d_in, const int* in_sizes, int n_in,
                              void* d_out, int out_size, void* d_ws, size_t ws_size,
                              hipStream_t stream) {
    const float* h0  = (const float*)d_in[0];
    const int*   src = (const int*)d_in[2];
    const int*   dst = (const int*)d_in[3];
    const int*   gid = (const int*)d_in[4];
    const float* eps = (const float*)d_in[5];
    const float* W1  = (const float*)d_in[6];
    const float* b1  = (const float*)d_in[7];
    const float* W2  = (const float*)d_in[8];
    const float* b2  = (const float*)d_in[9];
    const float* bn1g = (const float*)d_in[10];
    const float* bn1b = (const float*)d_in[11];
    const float* bn2g = (const float*)d_in[12];
    const float* bn2b = (const float*)d_in[13];
    const float* bn3g = (const float*)d_in[14];
    const float* bn3b = (const float*)d_in[15];
    const float* pW  = (const float*)d_in[16];
    const float* pb  = (const float*)d_in[17];

    const int N = in_sizes[0] / D;
    const int E = in_sizes[2];
    const size_t nd = (size_t)N * D;

    // ---- workspace layout
    float* z    = (float*)d_ws;              // N*D fp32
    u16*   hbf  = (u16*)(z + nd);            // N*D bf16
    u16*   xbf  = hbf + nd;                  // N*D bf16 (x, then y in-place)
    u16*   Wt   = xbf + nd;                  // 2L*D*D bf16
    float* stats = (float*)(Wt + (size_t)2 * L * D * D);  // L*3 pairs of [128+128]
    float* pooled0 = stats + (size_t)L * 3 * 2 * D;       // G*D
    int*   deg    = (int*)(pooled0 + (size_t)G * D);      // N
    int*   rowptr = deg + N;                 // N+1
    int*   cursor = rowptr + (N + 1);        // N
    int*   esrc   = cursor + N;              // E
    int*   bsum   = esrc + E;                // scan block sums

    float* score = (float*)d_out;
    float* pooledOut = score + G * OUT;      // pooled[1..4]

    auto S = [&](int i, int j) { return stats + (size_t)(i * 3 + j) * 2 * D; };
    auto Q = [&](int i, int j) { return stats + (size_t)(i * 3 + j) * 2 * D + D; };

    const int nb = (N + SCAN_CHUNK - 1) / SCAN_CHUNK;
    const int egrid = (E + 255) / 256;
    const int fgrid = (E + 2047) / 2048;
    const int nBuckets = (N + (1 << 14) - 1) >> 14;
    const int poolGrid = (N + 63) / 64;
    const int ggrid = (N + 127) / 128;
    const int agrid = (N + 7) / 8;
    const long long n4 = (long long)N * (D / 4);
    const float invN = 1.0f / (float)N;

    // one memset covers stats + pooled0 + deg (contiguous)
    const size_t zeroBytes = ((size_t)L * 3 * 2 * D + (size_t)G * D) * sizeof(float) + (size_t)N * sizeof(int);
    hipMemsetAsync(stats, 0, zeroBytes, stream);
    hipMemsetAsync(d_out, 0, (size_t)out_size * sizeof(float), stream);

    // ---- CSR build + weight prep
    edge_hist<<<egrid, 256, 0, stream>>>(dst, deg, E);
    prep_weights<<<2 * L, 256, 0, stream>>>(W1, W2, Wt);
    scan_pass1<<<nb, SCAN_B, 0, stream>>>(deg, rowptr, bsum, N);
    scan_pass2<<<1, 64, 0, stream>>>(bsum, nb);
    scan_pass3<<<nb, SCAN_B, 0, stream>>>(rowptr, bsum, N, E);
    hipMemcpyAsync(cursor, rowptr, (size_t)N * sizeof(int), hipMemcpyDeviceToDevice, stream);
    csr_fill<<<fgrid, 256, 0, stream>>>(src, dst, cursor, esrc, E, nBuckets);

    // ---- h0 -> bf16 + pool0
    convert_pool<<<poolGrid, 256, 0, stream>>>(h0, gid, hbf, pooled0, N);

    for (int i = 0; i < L; ++i) {
        agg_gather<<<agrid, 256, 0, stream>>>(hbf, rowptr, esrc, eps + i, xbf, N);

        // y = x @ W1 + b1 (bf16, in place on xbf) + stats P0
        gemm_mfma<2, true><<<ggrid, 256, 0, stream>>>(
            xbf, Wt + (size_t)i * D * D, b1 + (size_t)i * D,
            nullptr, nullptr, nullptr, nullptr, invN,
            (void*)xbf, S(i, 0), Q(i, 0), N);

        // z = relu(bn1(y)) @ W2 + b2 (fp32) + stats P1
        gemm_mfma<1, false><<<ggrid, 256, 0, stream>>>(
            xbf, Wt + (size_t)(L + i) * D * D, b2 + (size_t)i * D,
            S(i, 0), Q(i, 0), bn1g + (size_t)i * D, bn1b + (size_t)i * D, invN,
            (void*)z, S(i, 1), Q(i, 1), N);

        // stats P2 of relu(bn2(z))
        relu_bn_stats<<<1024, 256, 0, stream>>>(
            z, S(i, 1), Q(i, 1), bn2g + (size_t)i * D, bn2b + (size_t)i * D, invN,
            S(i, 2), Q(i, 2), n4);

        // h = relu(bn3(relu(bn2(z)))) -> hbf + pooled
        final_apply_pool<<<poolGrid, 256, 0, stream>>>(
            z, gid,
            S(i, 1), Q(i, 1), bn2g + (size_t)i * D, bn2b + (size_t)i * D,
            S(i, 2), Q(i, 2), bn3g + (size_t)i * D, bn3b + (size_t)i * D,
            invN, hbf, pooledOut + (size_t)i * G * D, N);
    }

    pred_heads<<<(G * OUT + 255) / 256, 256, 0, stream>>>(pooled0, pooledOut, pW, pb, score);
}

// Round 5
// 1147.741 us; speedup vs baseline: 10.6565x; 1.1465x over previous
//
#include <hip/hip_runtime.h>

constexpr int D   = 128;
constexpr int G   = 64;
constexpr int OUT = 64;
constexpr int L   = 4;
#define BN_EPS 1e-5f

typedef __attribute__((ext_vector_type(8))) short bf16x8;
typedef __attribute__((ext_vector_type(4))) short short4v;
typedef __attribute__((ext_vector_type(4))) float f32x4;
typedef unsigned short u16;

__device__ inline u16 f2bf(float f) {
    union { float f; unsigned u; } x; x.f = f;
    unsigned r = x.u + 0x7FFF + ((x.u >> 16) & 1);   // RNE
    return (u16)(r >> 16);
}
__device__ inline float bf2f(u16 u) {
    union { unsigned u; float f; } x; x.u = ((unsigned)u) << 16;
    return x.f;
}

// ================================================================ CSR build
// XCD-class partitioning: class(e) = (dst>>11)&7. Blocks with blockIdx&7==c
// (round-robin dispatch -> same XCD) touch only class-c deg/cursor/esrc lines,
// so hot windows stay in ONE XCD's L2 (no cross-XCD line bouncing).
constexpr int EH_CHUNK = 16384;

__global__ __launch_bounds__(256) void edge_hist(const int* __restrict__ dst,
                                                 int* __restrict__ deg, int nE) {
    const int cls = blockIdx.x & 7;
    const int base = (blockIdx.x >> 3) * EH_CHUNK;
    const int lim = min(base + EH_CHUNK, nE);
    for (int e = base + threadIdx.x; e < lim; e += 256) {
        int d = dst[e];
        if (((d >> 11) & 7) == cls) atomicAdd(&deg[d], 1);
    }
}

__global__ __launch_bounds__(256) void csr_fill(const int* __restrict__ src,
                                                const int* __restrict__ dst,
                                                int* __restrict__ cursor, int* __restrict__ esrc,
                                                int nE) {
    const int cls = blockIdx.x & 7;
    const int base = (blockIdx.x >> 3) * EH_CHUNK;
    const int lim = min(base + EH_CHUNK, nE);
    for (int e = base + threadIdx.x; e < lim; e += 256) {
        int d = dst[e];
        if (((d >> 11) & 7) == cls) {
            int pos = atomicAdd(&cursor[d], 1);
            esrc[pos] = src[e];
        }
    }
}

constexpr int SCAN_B = 256;
constexpr int SCAN_E = 8;
constexpr int SCAN_CHUNK = SCAN_B * SCAN_E;

__global__ __launch_bounds__(SCAN_B) void scan_pass1(const int* __restrict__ deg,
                                                     int* __restrict__ rowptr,
                                                     int* __restrict__ bsum, int n) {
    __shared__ int sm[SCAN_B];
    const int tid = threadIdx.x;
    const int base = blockIdx.x * SCAN_CHUNK + tid * SCAN_E;
    int v[SCAN_E];
    int s = 0;
#pragma unroll
    for (int j = 0; j < SCAN_E; ++j) {
        v[j] = (base + j < n) ? deg[base + j] : 0;
        s += v[j];
    }
    sm[tid] = s;
    __syncthreads();
    for (int off = 1; off < SCAN_B; off <<= 1) {
        int t = (tid >= off) ? sm[tid - off] : 0;
        __syncthreads();
        sm[tid] += t;
        __syncthreads();
    }
    int run = sm[tid] - s;
#pragma unroll
    for (int j = 0; j < SCAN_E; ++j) {
        if (base + j < n) rowptr[base + j] = run;
        run += v[j];
    }
    if (tid == SCAN_B - 1) bsum[blockIdx.x] = sm[SCAN_B - 1];
}

__global__ void scan_pass2(int* __restrict__ bsum, int nb) {
    if (threadIdx.x == 0 && blockIdx.x == 0) {
        int t = 0;
        for (int i = 0; i < nb; ++i) {
            int s = bsum[i];
            bsum[i] = t;
            t += s;
        }
    }
}

__global__ __launch_bounds__(SCAN_B) void scan_pass3(int* __restrict__ rowptr,
                                                     const int* __restrict__ bsum,
                                                     int n, int total) {
    const int add = bsum[blockIdx.x];
    const int base = blockIdx.x * SCAN_CHUNK + threadIdx.x * SCAN_E;
#pragma unroll
    for (int j = 0; j < SCAN_E; ++j)
        if (base + j < n) rowptr[base + j] += add;
    if (blockIdx.x == 0 && threadIdx.x == 0) rowptr[n] = total;
}

// ================================================================ weights -> bf16 transposed: Wt[mat][col][k]
__global__ void prep_weights(const float* __restrict__ W1, const float* __restrict__ W2,
                             u16* __restrict__ Wt) {
    const int m = blockIdx.x;  // 0..2L-1
    const float* W = (m < L) ? (W1 + (size_t)m * D * D) : (W2 + (size_t)(m - L) * D * D);
    u16* o = Wt + (size_t)m * D * D;
    for (int e = threadIdx.x * 4; e < D * D; e += 256 * 4) {
        float4 v = *reinterpret_cast<const float4*>(W + e);
        int k = e >> 7, c = e & 127;
        o[(c + 0) * D + k] = f2bf(v.x);
        o[(c + 1) * D + k] = f2bf(v.y);
        o[(c + 2) * D + k] = f2bf(v.z);
        o[(c + 3) * D + k] = f2bf(v.w);
    }
}

// ================================================================ h0 -> bf16 + pool0
__global__ __launch_bounds__(256) void convert_pool(const float* __restrict__ h, const int* __restrict__ gid,
                                                    u16* __restrict__ hbf, float* __restrict__ pooled,
                                                    int nRows) {
    const int tid = threadIdx.x;
    const int c = tid & 127;
    const int rsub = tid >> 7;
    const long long row0 = (long long)blockIdx.x * 64;
    float acc = 0.f;
    int cur = -1;
    for (int r = rsub; r < 64; r += 2) {
        long long row = row0 + r;
        if (row >= nRows) break;
        float v = h[row * D + c];
        hbf[row * D + c] = f2bf(v);
        int g = gid[row];
        if (g != cur) {
            if (cur >= 0) atomicAdd(&pooled[(long long)cur * D + c], acc);
            cur = g;
            acc = 0.f;
        }
        acc += v;
    }
    if (cur >= 0) atomicAdd(&pooled[(long long)cur * D + c], acc);
}

// ================================================================ aggregation (bf16 gather, 4-deep MLP) + GIN combine
__global__ __launch_bounds__(256) void agg_gather(const u16* __restrict__ hbf,
                                                  const int* __restrict__ rowptr,
                                                  const int* __restrict__ esrc,
                                                  const float* __restrict__ epsP,
                                                  u16* __restrict__ xbf, int nRows) {
    const int r = blockIdx.x * 8 + (threadIdx.x >> 5);
    if (r >= nRows) return;
    const int c = (threadIdx.x & 31) * 4;
    const int beg = rowptr[r], end = rowptr[r + 1];
    const float ep = 1.0f + epsP[0];
    short4v a = *reinterpret_cast<const short4v*>(hbf + (size_t)r * D + c);
    float acc[4];
#pragma unroll
    for (int j = 0; j < 4; ++j) acc[j] = ep * bf2f((u16)a[j]);

    int e = beg;
    for (; e + 4 <= end; e += 4) {
        int s0 = esrc[e + 0], s1 = esrc[e + 1], s2 = esrc[e + 2], s3 = esrc[e + 3];
        short4v v0 = *reinterpret_cast<const short4v*>(hbf + (size_t)s0 * D + c);
        short4v v1 = *reinterpret_cast<const short4v*>(hbf + (size_t)s1 * D + c);
        short4v v2 = *reinterpret_cast<const short4v*>(hbf + (size_t)s2 * D + c);
        short4v v3 = *reinterpret_cast<const short4v*>(hbf + (size_t)s3 * D + c);
#pragma unroll
        for (int j = 0; j < 4; ++j)
            acc[j] += (bf2f((u16)v0[j]) + bf2f((u16)v1[j])) + (bf2f((u16)v2[j]) + bf2f((u16)v3[j]));
    }
    for (; e < end; ++e) {
        int s = esrc[e];
        short4v v = *reinterpret_cast<const short4v*>(hbf + (size_t)s * D + c);
#pragma unroll
        for (int j = 0; j < 4; ++j) acc[j] += bf2f((u16)v[j]);
    }
    short4v o;
#pragma unroll
    for (int j = 0; j < 4; ++j) o[j] = (short)f2bf(acc[j]);
    *reinterpret_cast<short4v*>(xbf + (size_t)r * D + c) = o;
}

// ================================================================ MFMA GEMM, bf16 A/out (128-tile), bf16 Wt [col][k], BN-stat epilogue
// MODE 1: A = relu(bn(in)) from prev raw stats; MODE 2: A = in.
// Stats accumulated on fp32 pre-round values. In-place (out==A) is safe:
// each block reads only rows [row0,row0+128) before writing them.
template <int MODE>
__global__ __launch_bounds__(256) void gemm_mfma(
    const u16* __restrict__ A, const u16* __restrict__ Wt, const float* __restrict__ bias,
    const float* __restrict__ pSum, const float* __restrict__ pSq,
    const float* __restrict__ bng, const float* __restrict__ bnb, float invN,
    u16* __restrict__ outP, float* __restrict__ gsum, float* __restrict__ gsq,
    int nRows) {
    __shared__ u16 wL[D * D];   // 32 KB swizzled [col][k]
    __shared__ u16 aL[D * D];   // 32 KB swizzled [row][k]
    __shared__ float redS[D], redQ[D];
    __shared__ float scL[D], shL[D];

    const int tid = threadIdx.x;
    const int row0 = blockIdx.x * 128;

    if (tid < D) {
        redS[tid] = 0.f; redQ[tid] = 0.f;
        if (MODE == 1) {
            float m = pSum[tid] * invN;
            float v = pSq[tid] * invN - m * m;
            float sc = bng[tid] * rsqrtf(v + BN_EPS);
            scL[tid] = sc;
            shL[tid] = bnb[tid] - m * sc;
        }
    }
    if (MODE == 1) __syncthreads();  // scL/shL ready before staging reads

    for (int o = tid * 8; o < D * D; o += 2048) {
        bf16x8 v = *reinterpret_cast<const bf16x8*>(Wt + o);
        int byte = o * 2, r = byte >> 8;
        *reinterpret_cast<bf16x8*>((char*)wL + (byte ^ ((r & 7) << 4))) = v;
    }
#pragma unroll
    for (int it = 0; it < 8; ++it) {
        int o = (it * 256 + tid) * 8;
        int r = o >> 7, c = o & 127;
        int grow = row0 + r;
        bf16x8 v = {};
        if (grow < nRows) {
            v = *reinterpret_cast<const bf16x8*>(A + (size_t)grow * D + c);
            if (MODE == 1) {
#pragma unroll
                for (int j = 0; j < 8; ++j) {
                    float t = fmaxf(bf2f((u16)v[j]) * scL[c + j] + shL[c + j], 0.f);
                    v[j] = (short)f2bf(t);
                }
            }
        }
        int byte = o * 2;
        *reinterpret_cast<bf16x8*>((char*)aL + (byte ^ ((r & 7) << 4))) = v;
    }
    __syncthreads();

    const int lane = tid & 63;
    const int wv = tid >> 6;
    const int wrow = wv * 32;
    const int lr = lane & 15;
    const int lb = lane >> 4;

    f32x4 acc[2][8] = {};
#pragma unroll
    for (int kk = 0; kk < 4; ++kk) {
        bf16x8 aF[2];
#pragma unroll
        for (int m = 0; m < 2; ++m) {
            int r = wrow + m * 16 + lr;
            int byte = r * 256 + kk * 64 + lb * 16;
            aF[m] = *reinterpret_cast<const bf16x8*>((char*)aL + (byte ^ ((r & 7) << 4)));
        }
#pragma unroll
        for (int n = 0; n < 8; ++n) {
            int cr = n * 16 + lr;
            int byte = cr * 256 + kk * 64 + lb * 16;
            bf16x8 bF = *reinterpret_cast<const bf16x8*>((char*)wL + (byte ^ ((cr & 7) << 4)));
            acc[0][n] = __builtin_amdgcn_mfma_f32_16x16x32_bf16(aF[0], bF, acc[0][n], 0, 0, 0);
            acc[1][n] = __builtin_amdgcn_mfma_f32_16x16x32_bf16(aF[1], bF, acc[1][n], 0, 0, 0);
        }
    }

    float ls[8], lq[8];
#pragma unroll
    for (int n = 0; n < 8; ++n) { ls[n] = 0.f; lq[n] = 0.f; }
#pragma unroll
    for (int n = 0; n < 8; ++n) {
        int col = n * 16 + lr;
        float bv = bias[col];
#pragma unroll
        for (int m = 0; m < 2; ++m) {
#pragma unroll
            for (int j = 0; j < 4; ++j) {
                int row = row0 + wrow + m * 16 + lb * 4 + j;
                if (row < nRows) {
                    float o = acc[m][n][j] + bv;
                    outP[(size_t)row * D + col] = f2bf(o);
                    ls[n] += o; lq[n] += o * o;
                }
            }
        }
    }
#pragma unroll
    for (int n = 0; n < 8; ++n) {
        int col = n * 16 + lr;
        atomicAdd(&redS[col], ls[n]);
        atomicAdd(&redQ[col], lq[n]);
    }
    __syncthreads();
    if (tid < D) {
        atomicAdd(&gsum[tid], redS[tid]);
        atomicAdd(&gsq[tid], redQ[tid]);
    }
}

// ================================================================ stats of relu(bn2(z)), z in bf16; scale/shift computed in-kernel
__global__ __launch_bounds__(256) void relu_bn_stats(const u16* __restrict__ z,
                                                     const float* __restrict__ pSum, const float* __restrict__ pSq,
                                                     const float* __restrict__ bng, const float* __restrict__ bnb,
                                                     float invN,
                                                     float* __restrict__ gsum, float* __restrict__ gsq,
                                                     long long n8) {
    __shared__ float redS[D], redQ[D];
    const int tid = threadIdx.x;
    if (tid < D) { redS[tid] = 0.f; redQ[tid] = 0.f; }
    __syncthreads();
    const int c = (tid & 15) * 8;
    float sc[8], sh[8];
#pragma unroll
    for (int j = 0; j < 8; ++j) {
        float m = pSum[c + j] * invN;
        float v = pSq[c + j] * invN - m * m;
        float s = bng[c + j] * rsqrtf(v + BN_EPS);
        sc[j] = s;
        sh[j] = bnb[c + j] - m * s;
    }
    const long long stride = (long long)gridDim.x * blockDim.x;
    float ls[8] = {}, lq[8] = {};
    for (long long i = (long long)blockIdx.x * blockDim.x + tid; i < n8; i += stride) {
        bf16x8 v = *reinterpret_cast<const bf16x8*>(z + i * 8);
#pragma unroll
        for (int j = 0; j < 8; ++j) {
            float t = fmaxf(bf2f((u16)v[j]) * sc[j] + sh[j], 0.f);
            ls[j] += t; lq[j] += t * t;
        }
    }
#pragma unroll
    for (int j = 0; j < 8; ++j) {
        atomicAdd(&redS[c + j], ls[j]);
        atomicAdd(&redQ[c + j], lq[j]);
    }
    __syncthreads();
    if (tid < D) {
        atomicAdd(&gsum[tid], redS[tid]);
        atomicAdd(&gsq[tid], redQ[tid]);
    }
}

// ================================================================ h = relu(bn3(relu(bn2(z)))) -> hbf (bf16) + pooling (fp32)
__global__ __launch_bounds__(256) void final_apply_pool(
    const u16* __restrict__ z, const int* __restrict__ gid,
    const float* __restrict__ p1S, const float* __restrict__ p1Q,
    const float* __restrict__ g2, const float* __restrict__ b2v,
    const float* __restrict__ p2S, const float* __restrict__ p2Q,
    const float* __restrict__ g3, const float* __restrict__ b3v,
    float invN, u16* __restrict__ hbf, float* __restrict__ pooled, int nRows) {
    const int tid = threadIdx.x;
    const int c = tid & 127;
    const int rsub = tid >> 7;
    const long long row0 = (long long)blockIdx.x * 64;

    float m = p1S[c] * invN;
    float va = p1Q[c] * invN - m * m;
    float a2 = g2[c] * rsqrtf(va + BN_EPS);
    float f2v = b2v[c] - m * a2;
    m = p2S[c] * invN;
    va = p2Q[c] * invN - m * m;
    float a3 = g3[c] * rsqrtf(va + BN_EPS);
    float f3v = b3v[c] - m * a3;

    float acc = 0.f;
    int cur = -1;
    for (int r = rsub; r < 64; r += 2) {
        long long row = row0 + r;
        if (row >= nRows) break;
        float v = bf2f(z[row * D + c]);
        v = fmaxf(fmaxf(v * a2 + f2v, 0.f) * a3 + f3v, 0.f);
        hbf[row * D + c] = f2bf(v);
        int g = gid[row];
        if (g != cur) {
            if (cur >= 0) atomicAdd(&pooled[(long long)cur * D + c], acc);
            cur = g;
            acc = 0.f;
        }
        acc += v;
    }
    if (cur >= 0) atomicAdd(&pooled[(long long)cur * D + c], acc);
}

// ================================================================ prediction heads
__global__ void pred_heads(const float* __restrict__ pooled0, const float* __restrict__ pooledL,
                           const float* __restrict__ pW, const float* __restrict__ pb,
                           float* __restrict__ score) {
    int idx = blockIdx.x * blockDim.x + threadIdx.x;
    if (idx >= G * OUT) return;
    int g = idx >> 6, o = idx & 63;
    float acc = 0.f;
    for (int i = 0; i <= L; ++i) {
        const float* p = (i == 0) ? (pooled0 + (long long)g * D)
                                  : (pooledL + (long long)(i - 1) * G * D + (long long)g * D);
        const float* w = pW + (long long)i * D * OUT + o;
        float s = 0.f;
#pragma unroll 4
        for (int k = 0; k < D; ++k) s += p[k] * w[(long long)k * OUT];
        acc += s + pb[i * OUT + o];
    }
    score[idx] = acc;
}

// ================================================================
extern "C" void kernel_launch(void* const* d_in, const int* in_sizes, int n_in,
                              void* d_out, int out_size, void* d_ws, size_t ws_size,
                              hipStream_t stream) {
    const float* h0  = (const float*)d_in[0];
    const int*   src = (const int*)d_in[2];
    const int*   dst = (const int*)d_in[3];
    const int*   gid = (const int*)d_in[4];
    const float* eps = (const float*)d_in[5];
    const float* W1  = (const float*)d_in[6];
    const float* b1  = (const float*)d_in[7];
    const float* W2  = (const float*)d_in[8];
    const float* b2  = (const float*)d_in[9];
    const float* bn1g = (const float*)d_in[10];
    const float* bn1b = (const float*)d_in[11];
    const float* bn2g = (const float*)d_in[12];
    const float* bn2b = (const float*)d_in[13];
    const float* bn3g = (const float*)d_in[14];
    const float* bn3b = (const float*)d_in[15];
    const float* pW  = (const float*)d_in[16];
    const float* pb  = (const float*)d_in[17];

    const int N = in_sizes[0] / D;
    const int E = in_sizes[2];
    const size_t nd = (size_t)N * D;

    // ---- workspace layout
    u16*   hbf  = (u16*)d_ws;                // N*D bf16
    u16*   xbf  = hbf + nd;                  // N*D bf16 (x -> y -> z in place)
    u16*   Wt   = xbf + nd;                  // 2L*D*D bf16
    float* stats = (float*)(Wt + (size_t)2 * L * D * D);  // L*3 pairs of [128+128]
    float* pooled0 = stats + (size_t)L * 3 * 2 * D;       // G*D
    int*   deg    = (int*)(pooled0 + (size_t)G * D);      // N
    int*   rowptr = deg + N;                 // N+1
    int*   cursor = rowptr + (N + 1);        // N
    int*   esrc   = cursor + N;              // E
    int*   bsum   = esrc + E;                // scan block sums

    float* score = (float*)d_out;
    float* pooledOut = score + G * OUT;      // pooled[1..4]

    auto S = [&](int i, int j) { return stats + (size_t)(i * 3 + j) * 2 * D; };
    auto Q = [&](int i, int j) { return stats + (size_t)(i * 3 + j) * 2 * D + D; };

    const int nb = (N + SCAN_CHUNK - 1) / SCAN_CHUNK;
    const int nChunks = (E + EH_CHUNK - 1) / EH_CHUNK;
    const int egrid = nChunks * 8;
    const int poolGrid = (N + 63) / 64;
    const int ggrid = (N + 127) / 128;
    const int agrid = (N + 7) / 8;
    const long long n8 = (long long)N * (D / 8);
    const float invN = 1.0f / (float)N;

    // one memset covers stats + pooled0 + deg (contiguous)
    const size_t zeroBytes = ((size_t)L * 3 * 2 * D + (size_t)G * D) * sizeof(float) + (size_t)N * sizeof(int);
    hipMemsetAsync(stats, 0, zeroBytes, stream);
    hipMemsetAsync(d_out, 0, (size_t)out_size * sizeof(float), stream);

    // ---- CSR build + weight prep
    edge_hist<<<egrid, 256, 0, stream>>>(dst, deg, E);
    prep_weights<<<2 * L, 256, 0, stream>>>(W1, W2, Wt);
    scan_pass1<<<nb, SCAN_B, 0, stream>>>(deg, rowptr, bsum, N);
    scan_pass2<<<1, 64, 0, stream>>>(bsum, nb);
    scan_pass3<<<nb, SCAN_B, 0, stream>>>(rowptr, bsum, N, E);
    hipMemcpyAsync(cursor, rowptr, (size_t)N * sizeof(int), hipMemcpyDeviceToDevice, stream);
    csr_fill<<<egrid, 256, 0, stream>>>(src, dst, cursor, esrc, E);

    // ---- h0 -> bf16 + pool0
    convert_pool<<<poolGrid, 256, 0, stream>>>(h0, gid, hbf, pooled0, N);

    for (int i = 0; i < L; ++i) {
        agg_gather<<<agrid, 256, 0, stream>>>(hbf, rowptr, esrc, eps + i, xbf, N);

        // y = x @ W1 + b1 (bf16, in place on xbf) + stats P0
        gemm_mfma<2><<<ggrid, 256, 0, stream>>>(
            xbf, Wt + (size_t)i * D * D, b1 + (size_t)i * D,
            nullptr, nullptr, nullptr, nullptr, invN,
            xbf, S(i, 0), Q(i, 0), N);

        // z = relu(bn1(y)) @ W2 + b2 (bf16, in place on xbf) + stats P1
        gemm_mfma<1><<<ggrid, 256, 0, stream>>>(
            xbf, Wt + (size_t)(L + i) * D * D, b2 + (size_t)i * D,
            S(i, 0), Q(i, 0), bn1g + (size_t)i * D, bn1b + (size_t)i * D, invN,
            xbf, S(i, 1), Q(i, 1), N);

        // stats P2 of relu(bn2(z))
        relu_bn_stats<<<1024, 256, 0, stream>>>(
            xbf, S(i, 1), Q(i, 1), bn2g + (size_t)i * D, bn2b + (size_t)i * D, invN,
            S(i, 2), Q(i, 2), n8);

        // h = relu(bn3(relu(bn2(z)))) -> hbf + pooled
        final_apply_pool<<<poolGrid, 256, 0, stream>>>(
            xbf, gid,
            S(i, 1), Q(i, 1), bn2g + (size_t)i * D, bn2b + (size_t)i * D,
            S(i, 2), Q(i, 2), bn3g + (size_t)i * D, bn3b + (size_t)i * D,
            invN, hbf, pooledOut + (size_t)i * G * D, N);
    }

    pred_heads<<<(G * OUT + 255) / 256, 256, 0, stream>>>(pooled0, pooledOut, pW, pb, score);
}